// Round 7
// baseline (187.588 us; speedup 1.0000x reference)
//
#include <hip/hip_runtime.h>
#include <hip/hip_bf16.h>
#include <cstdint>
#include <cstddef>

#define NSRC 100000
#define NDST 50000
#define DOUT 128
#define KK2 256   // 2*D

typedef __attribute__((ext_vector_type(8))) short bf16x8;
typedef __attribute__((ext_vector_type(4))) float f32x4;

static __device__ __forceinline__ unsigned short f2bf(float f) {
    union { float f; uint32_t u; } v; v.f = f;
    uint32_t u = v.u;
    uint32_t r = u + 0x7FFFu + ((u >> 16) & 1u);   // round-to-nearest-even
    return (unsigned short)(r >> 16);
}
static __device__ __forceinline__ float bf_lo(uint32_t u) {
    union { uint32_t x; float f; } v; v.x = u << 16; return v.f;
}
static __device__ __forceinline__ float bf_hi(uint32_t u) {
    union { uint32_t x; float f; } v; v.x = u & 0xFFFF0000u; return v.f;
}

// ---------------- K1: prep — WT bf16 convert + zero counters ----------------
__global__ __launch_bounds__(256) void k_prep(const float* __restrict__ W,
                                              unsigned short* __restrict__ WT,
                                              int* __restrict__ cnt,
                                              int* __restrict__ cnt2) {
    int i = blockIdx.x * 256 + threadIdx.x;
    if (i < DOUT * KK2) {
        int n = i >> 8;    // output col
        int k = i & 255;   // k index
        WT[i] = f2bf(W[k * DOUT + n]);
    }
    if (i < NDST) { cnt[i] = 0; cnt2[i] = 0; }
}

// ---------------- K2: hdelta_bf16 = bf16(H_src - HBar_src), fused dst histogram ----------------
__global__ __launch_bounds__(256) void k_hd_hist(const float4* __restrict__ a,
                                                 const float4* __restrict__ b,
                                                 ushort4* __restrict__ o,
                                                 const int* __restrict__ dst,
                                                 int* __restrict__ cnt,
                                                 int E, int n4) {
    int i = blockIdx.x * 256 + threadIdx.x;
    if (i < E) atomicAdd(&cnt[dst[i]], 1);   // fire-and-forget, hides under streaming
    if (i < n4) {
        float4 x = a[i], y = b[i];
        ushort4 u;
        u.x = f2bf(x.x - y.x); u.y = f2bf(x.y - y.y);
        u.z = f2bf(x.z - y.z); u.w = f2bf(x.w - y.w);
        o[i] = u;
    }
}

// ---------------- K3a: per-block sums ----------------
__global__ __launch_bounds__(256) void k_scan1(const int* __restrict__ cnt,
                                               int* __restrict__ bsum, int n) {
    int i = blockIdx.x * 256 + threadIdx.x;
    int v = (i < n) ? cnt[i] : 0;
#pragma unroll
    for (int s = 1; s < 64; s <<= 1) v += __shfl_xor(v, s, 64);
    __shared__ int wsum[4];
    if ((threadIdx.x & 63) == 0) wsum[threadIdx.x >> 6] = v;
    __syncthreads();
    if (threadIdx.x == 0) bsum[blockIdx.x] = wsum[0] + wsum[1] + wsum[2] + wsum[3];
}

// ---------------- K3b: merged scan — each block derives its own base from bsum,
//                  then scans its 256 cnt values and writes off ----------------
__global__ __launch_bounds__(256) void k_scan23(const int* __restrict__ cnt,
                                                const int* __restrict__ bsum,
                                                int* __restrict__ off,
                                                int n, int nb, int E) {
    __shared__ int wsum[4], wex[4];
    __shared__ int base_s;
    int t = threadIdx.x;
    int lane = t & 63, w = t >> 6;

    // phase A: scan the (nb<=256) block sums; pick out exclusive value at blockIdx.x
    int bv = (t < nb) ? bsum[t] : 0;
    int x = bv;
#pragma unroll
    for (int s = 1; s < 64; s <<= 1) { int tt = __shfl_up(x, s, 64); if (lane >= s) x += tt; }
    if (lane == 63) wsum[w] = x;
    __syncthreads();
    if (t == 0) {
        int run = 0;
#pragma unroll
        for (int k = 0; k < 4; ++k) { wex[k] = run; run += wsum[k]; }
    }
    __syncthreads();
    if (t == (int)blockIdx.x) base_s = wex[w] + x - bv;   // exclusive sum of bsum[0..blockIdx)
    __syncthreads();
    int base = base_s;
    __syncthreads();   // protect wsum/wex reuse

    // phase B: scan this block's cnt slice
    int i = blockIdx.x * 256 + t;
    int v = (i < n) ? cnt[i] : 0;
    x = v;
#pragma unroll
    for (int s = 1; s < 64; s <<= 1) { int tt = __shfl_up(x, s, 64); if (lane >= s) x += tt; }
    if (lane == 63) wsum[w] = x;
    __syncthreads();
    if (t == 0) {
        int run = 0;
#pragma unroll
        for (int k = 0; k < 4; ++k) { wex[k] = run; run += wsum[k]; }
    }
    __syncthreads();
    if (i < n) off[i] = base + wex[w] + x - v;
    if (blockIdx.x == 0 && t == 0) off[n] = E;
}

// ---------------- K4: scatter src ids into dst-sorted buckets ----------------
__global__ void k_scatter(const int* __restrict__ src, const int* __restrict__ dst,
                          const int* __restrict__ off, int* __restrict__ cur,
                          int* __restrict__ idx, int E) {
    int e = blockIdx.x * blockDim.x + threadIdx.x;
    if (e < E) {
        int d = dst[e];
        int p = off[d] + atomicAdd(&cur[d], 1);
        idx[p] = src[e];
    }
}

// ---------------- K5: barrier-free gather-mean-agg -> Xn (h_neigh half, bf16) ----------------
// 4 waves/block, ONE dst row per wave, NO __syncthreads — waves retire independently,
// so degree imbalance is absorbed by occupancy instead of a block barrier.
// Lane-parallel idx prefetch (idx[c+lane] = 64 ids in one coalesced load), shfl
// broadcast, unroll-8 => 8 independent 256B row-gathers in flight per wave.
__global__ __launch_bounds__(256, 8) void k_gath(const uint32_t* __restrict__ hd,
                                                 const float2* __restrict__ agg,
                                                 const int* __restrict__ off,
                                                 const int* __restrict__ idx,
                                                 ushort2* __restrict__ Xn, int n) {
    int r = blockIdx.x * 4 + (threadIdx.x >> 6);
    if (r >= n) return;
    int lane = threadIdx.x & 63;
    int o0 = off[r], o1 = off[r + 1];
    float accx = 0.f, accy = 0.f;
    for (int c = o0; c < o1; c += 64) {
        int m = o1 - c; if (m > 64) m = 64;
        int myi = (lane < m) ? idx[c + lane] : 0;
        int jm = m & ~7;
        for (int j = 0; j < jm; j += 8) {
            int s0 = __shfl(myi, j + 0), s1 = __shfl(myi, j + 1);
            int s2 = __shfl(myi, j + 2), s3 = __shfl(myi, j + 3);
            int s4 = __shfl(myi, j + 4), s5 = __shfl(myi, j + 5);
            int s6 = __shfl(myi, j + 6), s7 = __shfl(myi, j + 7);
            uint32_t v0 = hd[(size_t)s0 * 64 + lane];
            uint32_t v1 = hd[(size_t)s1 * 64 + lane];
            uint32_t v2 = hd[(size_t)s2 * 64 + lane];
            uint32_t v3 = hd[(size_t)s3 * 64 + lane];
            uint32_t v4 = hd[(size_t)s4 * 64 + lane];
            uint32_t v5 = hd[(size_t)s5 * 64 + lane];
            uint32_t v6 = hd[(size_t)s6 * 64 + lane];
            uint32_t v7 = hd[(size_t)s7 * 64 + lane];
            accx += bf_lo(v0) + bf_lo(v1) + bf_lo(v2) + bf_lo(v3)
                  + bf_lo(v4) + bf_lo(v5) + bf_lo(v6) + bf_lo(v7);
            accy += bf_hi(v0) + bf_hi(v1) + bf_hi(v2) + bf_hi(v3)
                  + bf_hi(v4) + bf_hi(v5) + bf_hi(v6) + bf_hi(v7);
        }
        for (int j = jm; j < m; ++j) {
            int s = __shfl(myi, j);
            uint32_t v = hd[(size_t)s * 64 + lane];
            accx += bf_lo(v);
            accy += bf_hi(v);
        }
    }
    float inv = 1.0f / fmaxf((float)(o1 - o0), 1.0f);
    float2 g = agg[(size_t)r * 64 + lane];
    Xn[(size_t)r * 64 + lane] = make_ushort2(f2bf(g.x + accx * inv),
                                             f2bf(g.y + accy * inv));
}

// ---------------- K6: GEMM [NDST,256] x [256,128] + bias + relu ----------------
// A-operand: k<128 from H_dst (f32, converted in-register), k>=128 from Xn (bf16).
// block = 256 thr = 4 waves; block owns one 16-row M-tile; wave w owns cols [w*32,w*32+32).
__global__ __launch_bounds__(256) void k_gemm(const float4* __restrict__ Hd4,
                                              const unsigned short* __restrict__ Xn,
                                              const unsigned short* __restrict__ WT,
                                              const float* __restrict__ bias,
                                              float* __restrict__ out) {
    int mt = blockIdx.x;
    int w = threadIdx.x >> 6;
    int l = threadIdx.x & 63;
    int lr = l & 15, lg = l >> 4;
    int row = mt * 16 + lr;

    // A fragments: kk 0..3 -> H_dst cols lg*8+kk*32 ; kk 4..7 -> Xn cols lg*8+(kk-4)*32
    bf16x8 afrag[8];
    const float4* hrow = Hd4 + (size_t)row * 32;
#pragma unroll
    for (int kk = 0; kk < 4; ++kk) {
        int c4 = lg * 2 + kk * 8;       // float4 index of col lg*8+kk*32
        float4 p = hrow[c4], q = hrow[c4 + 1];
        bf16x8 a;
        a[0] = (short)f2bf(p.x); a[1] = (short)f2bf(p.y);
        a[2] = (short)f2bf(p.z); a[3] = (short)f2bf(p.w);
        a[4] = (short)f2bf(q.x); a[5] = (short)f2bf(q.y);
        a[6] = (short)f2bf(q.z); a[7] = (short)f2bf(q.w);
        afrag[kk] = a;
    }
    const bf16x8* xrow = reinterpret_cast<const bf16x8*>(Xn + (size_t)row * 128);
#pragma unroll
    for (int kk = 0; kk < 4; ++kk)
        afrag[4 + kk] = xrow[lg + kk * 4];

    const bf16x8* B0 = reinterpret_cast<const bf16x8*>(WT + (size_t)(w * 32 + lr) * KK2 + lg * 8);
    const bf16x8* B1 = reinterpret_cast<const bf16x8*>(WT + (size_t)(w * 32 + 16 + lr) * KK2 + lg * 8);

    f32x4 acc0 = {0.f, 0.f, 0.f, 0.f};
    f32x4 acc1 = {0.f, 0.f, 0.f, 0.f};
#pragma unroll
    for (int kk = 0; kk < 8; ++kk) {
        acc0 = __builtin_amdgcn_mfma_f32_16x16x32_bf16(afrag[kk], B0[kk * 4], acc0, 0, 0, 0);
        acc1 = __builtin_amdgcn_mfma_f32_16x16x32_bf16(afrag[kk], B1[kk * 4], acc1, 0, 0, 0);
    }

    int col0 = w * 32 + lr;
    int col1 = col0 + 16;
    float bi0 = bias[col0], bi1 = bias[col1];
    int rowb = mt * 16 + lg * 4;
#pragma unroll
    for (int j = 0; j < 4; ++j) {
        float v0 = acc0[j] + bi0;
        float v1 = acc1[j] + bi1;
        out[(size_t)(rowb + j) * DOUT + col0] = v0 > 0.f ? v0 : 0.f;
        out[(size_t)(rowb + j) * DOUT + col1] = v1 > 0.f ? v1 : 0.f;
    }
}

extern "C" void kernel_launch(void* const* d_in, const int* in_sizes, int n_in,
                              void* d_out, int out_size, void* d_ws, size_t ws_size,
                              hipStream_t stream) {
    const float* H_src    = (const float*)d_in[0];
    const float* H_dst    = (const float*)d_in[1];
    const float* HBar_src = (const float*)d_in[2];
    const float* agg      = (const float*)d_in[3];
    const float* W        = (const float*)d_in[4];
    const float* bias     = (const float*)d_in[5];
    const int*   src      = (const int*)d_in[6];
    const int*   dst      = (const int*)d_in[7];
    float* out = (float*)d_out;
    const int E = in_sizes[6];
    const int NB = (NDST + 255) / 256;   // 196

    // ws layout (byte offsets, 512-aligned):
    //   cnt    : 0          .. 200,000
    //   cnt2   : 200,192    .. 400,192
    //   off    : 400,384    .. 600,388   (NDST+1)
    //   bsum   : 600,576    .. 601,360   (196 i32)
    //   idx    : 602,624    .. 3,802,624 (E i32)
    //   WT     : 3,803,136  .. 3,868,672 (128*256 bf16)
    //   Xn     : 3,868,672  .. 16,668,672 (NDST*128 bf16)
    //   hd_bf  : 16,668,672 .. 42,268,672 (NSRC*128 bf16)
    char* ws = (char*)d_ws;
    int* cnt             = (int*)ws;
    int* cnt2            = (int*)(ws + 200192);
    int* off             = (int*)(ws + 400384);
    int* bsum            = (int*)(ws + 600576);
    int* idx_sorted      = (int*)(ws + 602624);
    unsigned short* WT   = (unsigned short*)(ws + 3803136);
    unsigned short* Xn   = (unsigned short*)(ws + 3868672);
    unsigned short* hdbf = (unsigned short*)(ws + 16668672);

    k_prep<<<NB, 256, 0, stream>>>(W, WT, cnt, cnt2);

    int n4 = NSRC * 32;
    k_hd_hist<<<(n4 + 255) / 256, 256, 0, stream>>>(
        (const float4*)H_src, (const float4*)HBar_src, (ushort4*)hdbf,
        dst, cnt, E, n4);

    k_scan1<<<NB, 256, 0, stream>>>(cnt, bsum, NDST);
    k_scan23<<<NB, 256, 0, stream>>>(cnt, bsum, off, NDST, NB, E);

    k_scatter<<<(E + 255) / 256, 256, 0, stream>>>(src, dst, off, cnt2, idx_sorted, E);

    k_gath<<<(NDST + 3) / 4, 256, 0, stream>>>(
        (const uint32_t*)hdbf, (const float2*)agg, off, idx_sorted,
        (ushort2*)Xn, NDST);

    k_gemm<<<NDST / 16, 256, 0, stream>>>(
        (const float4*)H_dst, Xn, WT, bias, out);
}

// Round 8
// 184.382 us; speedup vs baseline: 1.0174x; 1.0174x over previous
//
#include <hip/hip_runtime.h>
#include <hip/hip_bf16.h>
#include <cstdint>
#include <cstddef>

#define NSRC 100000
#define NDST 50000
#define DOUT 128
#define KK2 256   // 2*D

typedef __attribute__((ext_vector_type(8))) short bf16x8;
typedef __attribute__((ext_vector_type(4))) float f32x4;

static __device__ __forceinline__ unsigned short f2bf(float f) {
    union { float f; uint32_t u; } v; v.f = f;
    uint32_t u = v.u;
    uint32_t r = u + 0x7FFFu + ((u >> 16) & 1u);   // round-to-nearest-even
    return (unsigned short)(r >> 16);
}
static __device__ __forceinline__ float bf_lo(uint32_t u) {
    union { uint32_t x; float f; } v; v.x = u << 16; return v.f;
}
static __device__ __forceinline__ float bf_hi(uint32_t u) {
    union { uint32_t x; float f; } v; v.x = u & 0xFFFF0000u; return v.f;
}

// ---------------- K1: prep — WT bf16 convert + zero counters ----------------
__global__ __launch_bounds__(256) void k_prep(const float* __restrict__ W,
                                              unsigned short* __restrict__ WT,
                                              int* __restrict__ cnt,
                                              int* __restrict__ cnt2) {
    int i = blockIdx.x * 256 + threadIdx.x;
    if (i < DOUT * KK2) {
        int n = i >> 8;    // output col
        int k = i & 255;   // k index
        WT[i] = f2bf(W[k * DOUT + n]);
    }
    if (i < NDST) { cnt[i] = 0; cnt2[i] = 0; }
}

// ---------------- K2a: histogram of dst (standalone — atomics OFF the streaming path) ----------------
__global__ __launch_bounds__(256) void k_hist(const int* __restrict__ dst,
                                              int* __restrict__ cnt, int E) {
    int e = blockIdx.x * 256 + threadIdx.x;
    if (e < E) atomicAdd(&cnt[dst[e]], 1);
}

// ---------------- K2b: hdelta_bf16 = bf16(H_src - HBar_src), pure streaming ----------------
__global__ __launch_bounds__(256) void k_hdelta_bf(const float4* __restrict__ a,
                                                   const float4* __restrict__ b,
                                                   ushort4* __restrict__ o, int n4) {
    int i = blockIdx.x * 256 + threadIdx.x;
    if (i < n4) {
        float4 x = a[i], y = b[i];
        ushort4 u;
        u.x = f2bf(x.x - y.x); u.y = f2bf(x.y - y.y);
        u.z = f2bf(x.z - y.z); u.w = f2bf(x.w - y.w);
        o[i] = u;
    }
}

// ---------------- K3a: per-block sums ----------------
__global__ __launch_bounds__(256) void k_scan1(const int* __restrict__ cnt,
                                               int* __restrict__ bsum, int n) {
    int i = blockIdx.x * 256 + threadIdx.x;
    int v = (i < n) ? cnt[i] : 0;
#pragma unroll
    for (int s = 1; s < 64; s <<= 1) v += __shfl_xor(v, s, 64);
    __shared__ int wsum[4];
    if ((threadIdx.x & 63) == 0) wsum[threadIdx.x >> 6] = v;
    __syncthreads();
    if (threadIdx.x == 0) bsum[blockIdx.x] = wsum[0] + wsum[1] + wsum[2] + wsum[3];
}

// ---------------- K3b: merged scan — each block derives its own base from bsum,
//                  then scans its 256 cnt values and writes off ----------------
__global__ __launch_bounds__(256) void k_scan23(const int* __restrict__ cnt,
                                                const int* __restrict__ bsum,
                                                int* __restrict__ off,
                                                int n, int nb, int E) {
    __shared__ int wsum[4], wex[4];
    __shared__ int base_s;
    int t = threadIdx.x;
    int lane = t & 63, w = t >> 6;

    // phase A: scan the (nb<=256) block sums; pick out exclusive value at blockIdx.x
    int bv = (t < nb) ? bsum[t] : 0;
    int x = bv;
#pragma unroll
    for (int s = 1; s < 64; s <<= 1) { int tt = __shfl_up(x, s, 64); if (lane >= s) x += tt; }
    if (lane == 63) wsum[w] = x;
    __syncthreads();
    if (t == 0) {
        int run = 0;
#pragma unroll
        for (int k = 0; k < 4; ++k) { wex[k] = run; run += wsum[k]; }
    }
    __syncthreads();
    if (t == (int)blockIdx.x) base_s = wex[w] + x - bv;   // exclusive sum of bsum[0..blockIdx)
    __syncthreads();
    int base = base_s;
    __syncthreads();   // protect wsum/wex reuse

    // phase B: scan this block's cnt slice
    int i = blockIdx.x * 256 + t;
    int v = (i < n) ? cnt[i] : 0;
    x = v;
#pragma unroll
    for (int s = 1; s < 64; s <<= 1) { int tt = __shfl_up(x, s, 64); if (lane >= s) x += tt; }
    if (lane == 63) wsum[w] = x;
    __syncthreads();
    if (t == 0) {
        int run = 0;
#pragma unroll
        for (int k = 0; k < 4; ++k) { wex[k] = run; run += wsum[k]; }
    }
    __syncthreads();
    if (i < n) off[i] = base + wex[w] + x - v;
    if (blockIdx.x == 0 && t == 0) off[n] = E;
}

// ---------------- K4: scatter src ids into dst-sorted buckets ----------------
__global__ void k_scatter(const int* __restrict__ src, const int* __restrict__ dst,
                          const int* __restrict__ off, int* __restrict__ cur,
                          int* __restrict__ idx, int E) {
    int e = blockIdx.x * blockDim.x + threadIdx.x;
    if (e < E) {
        int d = dst[e];
        int p = off[d] + atomicAdd(&cur[d], 1);
        idx[p] = src[e];
    }
}

// ---------------- K5: fused gather-mean-agg + GEMM + bias + relu (round-6 verbatim) ----------------
// block = 1024 thr = 16 waves, owns 16 dst rows; ONE ROW PER WAVE.
// phase 1: wave w gathers row r0+w. Lane-parallel idx prefetch (idx[c+lane],
//          one coalesced load = 64 edge ids), broadcast via __shfl; unroll-8
//          => 8 independent 256B row-gathers in flight per wave.
// phase 2: waves 0..3 compute the 16x128 output tile via MFMA (idle waves park).
// LDS row stride 264 shorts: b128 reads 2-way bank aliased (free).
__global__ __launch_bounds__(1024, 8) void k_fused(const uint32_t* __restrict__ hd,
                                                   const float2* __restrict__ Hd,
                                                   const float2* __restrict__ agg,
                                                   const int* __restrict__ off,
                                                   const int* __restrict__ idx,
                                                   const unsigned short* __restrict__ WT,
                                                   const float* __restrict__ bias,
                                                   float* __restrict__ out) {
    __shared__ __align__(16) unsigned short xt[16][264];
    int r0 = blockIdx.x * 16;
    int w = threadIdx.x >> 6, lane = threadIdx.x & 63;

    // ---- phase 1: gather + mean + agg -> LDS x-tile (wave w -> row r0+w) ----
    int r = r0 + w;
    int o0 = off[r], o1 = off[r + 1];
    float accx = 0.f, accy = 0.f;
    for (int c = o0; c < o1; c += 64) {
        int m = o1 - c; if (m > 64) m = 64;
        int myi = (lane < m) ? idx[c + lane] : 0;
        int jm = m & ~7;
        for (int j = 0; j < jm; j += 8) {
            int s0 = __shfl(myi, j + 0), s1 = __shfl(myi, j + 1);
            int s2 = __shfl(myi, j + 2), s3 = __shfl(myi, j + 3);
            int s4 = __shfl(myi, j + 4), s5 = __shfl(myi, j + 5);
            int s6 = __shfl(myi, j + 6), s7 = __shfl(myi, j + 7);
            uint32_t v0 = hd[(size_t)s0 * 64 + lane];
            uint32_t v1 = hd[(size_t)s1 * 64 + lane];
            uint32_t v2 = hd[(size_t)s2 * 64 + lane];
            uint32_t v3 = hd[(size_t)s3 * 64 + lane];
            uint32_t v4 = hd[(size_t)s4 * 64 + lane];
            uint32_t v5 = hd[(size_t)s5 * 64 + lane];
            uint32_t v6 = hd[(size_t)s6 * 64 + lane];
            uint32_t v7 = hd[(size_t)s7 * 64 + lane];
            accx += bf_lo(v0) + bf_lo(v1) + bf_lo(v2) + bf_lo(v3)
                  + bf_lo(v4) + bf_lo(v5) + bf_lo(v6) + bf_lo(v7);
            accy += bf_hi(v0) + bf_hi(v1) + bf_hi(v2) + bf_hi(v3)
                  + bf_hi(v4) + bf_hi(v5) + bf_hi(v6) + bf_hi(v7);
        }
        for (int j = jm; j < m; ++j) {
            int s = __shfl(myi, j);
            uint32_t v = hd[(size_t)s * 64 + lane];
            accx += bf_lo(v);
            accy += bf_hi(v);
        }
    }
    float inv = 1.0f / fmaxf((float)(o1 - o0), 1.0f);
    float2 g = agg[(size_t)r * 64 + lane];
    float2 h = Hd[(size_t)r * 64 + lane];
    *(ushort2*)&xt[w][2 * lane]       = make_ushort2(f2bf(h.x), f2bf(h.y));
    *(ushort2*)&xt[w][128 + 2 * lane] = make_ushort2(f2bf(g.x + accx * inv),
                                                     f2bf(g.y + accy * inv));
    __syncthreads();

    // ---- phase 2: 16x128 GEMM tile, K=256 (waves 0..3 only) ----
    if (w < 4) {
        int lr = lane & 15, lg = lane >> 4;
        const bf16x8* B0 = reinterpret_cast<const bf16x8*>(WT + (size_t)(w * 32 + lr) * KK2 + lg * 8);
        const bf16x8* B1 = reinterpret_cast<const bf16x8*>(WT + (size_t)(w * 32 + 16 + lr) * KK2 + lg * 8);

        f32x4 acc0 = {0.f, 0.f, 0.f, 0.f};
        f32x4 acc1 = {0.f, 0.f, 0.f, 0.f};
#pragma unroll
        for (int kk = 0; kk < 8; ++kk) {
            bf16x8 av = *reinterpret_cast<const bf16x8*>(&xt[lr][lg * 8 + kk * 32]);
            acc0 = __builtin_amdgcn_mfma_f32_16x16x32_bf16(av, B0[kk * 4], acc0, 0, 0, 0);
            acc1 = __builtin_amdgcn_mfma_f32_16x16x32_bf16(av, B1[kk * 4], acc1, 0, 0, 0);
        }

        int col0 = w * 32 + lr;
        int col1 = col0 + 16;
        float bi0 = bias[col0], bi1 = bias[col1];
        int rowb = r0 + lg * 4;
#pragma unroll
        for (int j = 0; j < 4; ++j) {
            float v0 = acc0[j] + bi0;
            float v1 = acc1[j] + bi1;
            out[(size_t)(rowb + j) * DOUT + col0] = v0 > 0.f ? v0 : 0.f;
            out[(size_t)(rowb + j) * DOUT + col1] = v1 > 0.f ? v1 : 0.f;
        }
    }
}

extern "C" void kernel_launch(void* const* d_in, const int* in_sizes, int n_in,
                              void* d_out, int out_size, void* d_ws, size_t ws_size,
                              hipStream_t stream) {
    const float* H_src    = (const float*)d_in[0];
    const float* H_dst    = (const float*)d_in[1];
    const float* HBar_src = (const float*)d_in[2];
    const float* agg      = (const float*)d_in[3];
    const float* W        = (const float*)d_in[4];
    const float* bias     = (const float*)d_in[5];
    const int*   src      = (const int*)d_in[6];
    const int*   dst      = (const int*)d_in[7];
    float* out = (float*)d_out;
    const int E = in_sizes[6];
    const int NB = (NDST + 255) / 256;   // 196

    // ws layout (byte offsets, 512-aligned):
    //   cnt    : 0         .. 200,000
    //   cnt2   : 200,192   .. 400,192
    //   off    : 400,384   .. 600,388   (NDST+1)
    //   bsum   : 600,576   .. 601,360   (196 i32)
    //   idx    : 602,624   .. 3,802,624 (E i32)
    //   WT     : 3,803,136 .. 3,868,672 (128*256 bf16)
    //   hd_bf  : 3,868,672 .. 29,468,672 (NSRC*128 bf16)
    char* ws = (char*)d_ws;
    int* cnt             = (int*)ws;
    int* cnt2            = (int*)(ws + 200192);
    int* off             = (int*)(ws + 400384);
    int* bsum            = (int*)(ws + 600576);
    int* idx_sorted      = (int*)(ws + 602624);
    unsigned short* WT   = (unsigned short*)(ws + 3803136);
    unsigned short* hdbf = (unsigned short*)(ws + 3868672);

    k_prep<<<NB, 256, 0, stream>>>(W, WT, cnt, cnt2);

    k_hist<<<(E + 255) / 256, 256, 0, stream>>>(dst, cnt, E);

    int n4 = NSRC * 32;
    k_hdelta_bf<<<(n4 + 255) / 256, 256, 0, stream>>>(
        (const float4*)H_src, (const float4*)HBar_src, (ushort4*)hdbf, n4);

    k_scan1<<<NB, 256, 0, stream>>>(cnt, bsum, NDST);
    k_scan23<<<NB, 256, 0, stream>>>(cnt, bsum, off, NDST, NB, E);

    k_scatter<<<(E + 255) / 256, 256, 0, stream>>>(src, dst, off, cnt2, idx_sorted, E);

    k_fused<<<NDST / 16, 1024, 0, stream>>>(
        (const uint32_t*)hdbf, (const float2*)H_dst, (const float2*)agg,
        off, idx_sorted, WT, bias, out);
}

// Round 9
// 162.609 us; speedup vs baseline: 1.1536x; 1.1339x over previous
//
#include <hip/hip_runtime.h>
#include <hip/hip_bf16.h>
#include <cstdint>
#include <cstddef>

#define NSRC 100000
#define NDST 50000
#define DOUT 128
#define KK2 256   // 2*D

typedef __attribute__((ext_vector_type(8))) short bf16x8;
typedef __attribute__((ext_vector_type(4))) float f32x4;
typedef __attribute__((ext_vector_type(2))) float f32x2;

static __device__ __forceinline__ unsigned short f2bf(float f) {
    union { float f; uint32_t u; } v; v.f = f;
    uint32_t u = v.u;
    uint32_t r = u + 0x7FFFu + ((u >> 16) & 1u);   // round-to-nearest-even
    return (unsigned short)(r >> 16);
}

// ---------------- K1: prep — WT bf16 convert + zero counters ----------------
__global__ __launch_bounds__(256) void k_prep(const float* __restrict__ W,
                                              unsigned short* __restrict__ WT,
                                              int* __restrict__ cnt,
                                              int* __restrict__ cnt2) {
    int i = blockIdx.x * 256 + threadIdx.x;
    if (i < DOUT * KK2) {
        int n = i >> 8;    // output col
        int k = i & 255;   // k index
        WT[i] = f2bf(W[k * DOUT + n]);
    }
    if (i < NDST) { cnt[i] = 0; cnt2[i] = 0; }
}

// ---------------- K2: hdelta_fp8 = e4m3(H_src - HBar_src), fused dst histogram ----------------
// thread i handles 8 elements (two float4 pairs -> uint2 of 8 fp8)
__global__ __launch_bounds__(256) void k_hd_hist(const float4* __restrict__ a,
                                                 const float4* __restrict__ b,
                                                 uint2* __restrict__ o,
                                                 const int* __restrict__ dst,
                                                 int* __restrict__ cnt,
                                                 int E, int n8) {
    int i = blockIdx.x * 256 + threadIdx.x;
    if (i < E) atomicAdd(&cnt[dst[i]], 1);   // fire-and-forget
    if (i < n8) {
        float4 x0 = a[i * 2],     y0 = b[i * 2];
        float4 x1 = a[i * 2 + 1], y1 = b[i * 2 + 1];
        uint32_t p0 = __builtin_amdgcn_cvt_pk_fp8_f32(x0.x - y0.x, x0.y - y0.y, 0u, false);
        p0 = __builtin_amdgcn_cvt_pk_fp8_f32(x0.z - y0.z, x0.w - y0.w, p0, true);
        uint32_t p1 = __builtin_amdgcn_cvt_pk_fp8_f32(x1.x - y1.x, x1.y - y1.y, 0u, false);
        p1 = __builtin_amdgcn_cvt_pk_fp8_f32(x1.z - y1.z, x1.w - y1.w, p1, true);
        o[i] = make_uint2(p0, p1);
    }
}

// ---------------- K3a: per-block sums ----------------
__global__ __launch_bounds__(256) void k_scan1(const int* __restrict__ cnt,
                                               int* __restrict__ bsum, int n) {
    int i = blockIdx.x * 256 + threadIdx.x;
    int v = (i < n) ? cnt[i] : 0;
#pragma unroll
    for (int s = 1; s < 64; s <<= 1) v += __shfl_xor(v, s, 64);
    __shared__ int wsum[4];
    if ((threadIdx.x & 63) == 0) wsum[threadIdx.x >> 6] = v;
    __syncthreads();
    if (threadIdx.x == 0) bsum[blockIdx.x] = wsum[0] + wsum[1] + wsum[2] + wsum[3];
}

// ---------------- K3b: merged scan — each block derives its own base from bsum,
//                  then scans its 256 cnt values and writes off ----------------
__global__ __launch_bounds__(256) void k_scan23(const int* __restrict__ cnt,
                                                const int* __restrict__ bsum,
                                                int* __restrict__ off,
                                                int n, int nb, int E) {
    __shared__ int wsum[4], wex[4];
    __shared__ int base_s;
    int t = threadIdx.x;
    int lane = t & 63, w = t >> 6;

    // phase A: scan the (nb<=256) block sums; pick out exclusive value at blockIdx.x
    int bv = (t < nb) ? bsum[t] : 0;
    int x = bv;
#pragma unroll
    for (int s = 1; s < 64; s <<= 1) { int tt = __shfl_up(x, s, 64); if (lane >= s) x += tt; }
    if (lane == 63) wsum[w] = x;
    __syncthreads();
    if (t == 0) {
        int run = 0;
#pragma unroll
        for (int k = 0; k < 4; ++k) { wex[k] = run; run += wsum[k]; }
    }
    __syncthreads();
    if (t == (int)blockIdx.x) base_s = wex[w] + x - bv;   // exclusive sum of bsum[0..blockIdx)
    __syncthreads();
    int base = base_s;
    __syncthreads();   // protect wsum/wex reuse

    // phase B: scan this block's cnt slice
    int i = blockIdx.x * 256 + t;
    int v = (i < n) ? cnt[i] : 0;
    x = v;
#pragma unroll
    for (int s = 1; s < 64; s <<= 1) { int tt = __shfl_up(x, s, 64); if (lane >= s) x += tt; }
    if (lane == 63) wsum[w] = x;
    __syncthreads();
    if (t == 0) {
        int run = 0;
#pragma unroll
        for (int k = 0; k < 4; ++k) { wex[k] = run; run += wsum[k]; }
    }
    __syncthreads();
    if (i < n) off[i] = base + wex[w] + x - v;
    if (blockIdx.x == 0 && t == 0) off[n] = E;
}

// ---------------- K4: scatter src ids into dst-sorted buckets ----------------
__global__ void k_scatter(const int* __restrict__ src, const int* __restrict__ dst,
                          const int* __restrict__ off, int* __restrict__ cur,
                          int* __restrict__ idx, int E) {
    int e = blockIdx.x * blockDim.x + threadIdx.x;
    if (e < E) {
        int d = dst[e];
        int p = off[d] + atomicAdd(&cur[d], 1);
        idx[p] = src[e];
    }
}

// ---------------- K5: fused gather-mean-agg + GEMM + bias + relu ----------------
// block = 1024 thr = 16 waves, owns 16 dst rows; ONE ROW PER WAVE.
// phase 1: wave w gathers row r0+w from the fp8 table (lane owns cols 2l,2l+1 =
//          one ushort = 2 fp8; hardware cvt_pk_f32_fp8 decode). Lane-parallel idx
//          prefetch + shfl broadcast; unroll-8 => 8 independent 128B row-gathers
//          in flight per wave.
// phase 2: waves 0..3 compute the 16x128 output tile via MFMA (idle waves park).
__global__ __launch_bounds__(1024, 8) void k_fused(const unsigned short* __restrict__ hd8,
                                                   const float2* __restrict__ Hd,
                                                   const float2* __restrict__ agg,
                                                   const int* __restrict__ off,
                                                   const int* __restrict__ idx,
                                                   const unsigned short* __restrict__ WT,
                                                   const float* __restrict__ bias,
                                                   float* __restrict__ out) {
    __shared__ __align__(16) unsigned short xt[16][264];
    int r0 = blockIdx.x * 16;
    int w = threadIdx.x >> 6, lane = threadIdx.x & 63;

    // ---- phase 1: gather + mean + agg -> LDS x-tile (wave w -> row r0+w) ----
    int r = r0 + w;
    int o0 = off[r], o1 = off[r + 1];
    float accx = 0.f, accy = 0.f;
    for (int c = o0; c < o1; c += 64) {
        int m = o1 - c; if (m > 64) m = 64;
        int myi = (lane < m) ? idx[c + lane] : 0;
        int jm = m & ~7;
        for (int j = 0; j < jm; j += 8) {
            int s0 = __shfl(myi, j + 0), s1 = __shfl(myi, j + 1);
            int s2 = __shfl(myi, j + 2), s3 = __shfl(myi, j + 3);
            int s4 = __shfl(myi, j + 4), s5 = __shfl(myi, j + 5);
            int s6 = __shfl(myi, j + 6), s7 = __shfl(myi, j + 7);
            unsigned int u0 = hd8[(size_t)s0 * 64 + lane];
            unsigned int u1 = hd8[(size_t)s1 * 64 + lane];
            unsigned int u2 = hd8[(size_t)s2 * 64 + lane];
            unsigned int u3 = hd8[(size_t)s3 * 64 + lane];
            unsigned int u4 = hd8[(size_t)s4 * 64 + lane];
            unsigned int u5 = hd8[(size_t)s5 * 64 + lane];
            unsigned int u6 = hd8[(size_t)s6 * 64 + lane];
            unsigned int u7 = hd8[(size_t)s7 * 64 + lane];
            f32x2 d0 = __builtin_amdgcn_cvt_pk_f32_fp8(u0, false);
            f32x2 d1 = __builtin_amdgcn_cvt_pk_f32_fp8(u1, false);
            f32x2 d2 = __builtin_amdgcn_cvt_pk_f32_fp8(u2, false);
            f32x2 d3 = __builtin_amdgcn_cvt_pk_f32_fp8(u3, false);
            f32x2 d4 = __builtin_amdgcn_cvt_pk_f32_fp8(u4, false);
            f32x2 d5 = __builtin_amdgcn_cvt_pk_f32_fp8(u5, false);
            f32x2 d6 = __builtin_amdgcn_cvt_pk_f32_fp8(u6, false);
            f32x2 d7 = __builtin_amdgcn_cvt_pk_f32_fp8(u7, false);
            accx += d0[0] + d1[0] + d2[0] + d3[0] + d4[0] + d5[0] + d6[0] + d7[0];
            accy += d0[1] + d1[1] + d2[1] + d3[1] + d4[1] + d5[1] + d6[1] + d7[1];
        }
        for (int j = jm; j < m; ++j) {
            int s = __shfl(myi, j);
            unsigned int u = hd8[(size_t)s * 64 + lane];
            f32x2 d = __builtin_amdgcn_cvt_pk_f32_fp8(u, false);
            accx += d[0];
            accy += d[1];
        }
    }
    float inv = 1.0f / fmaxf((float)(o1 - o0), 1.0f);
    float2 g = agg[(size_t)r * 64 + lane];
    float2 h = Hd[(size_t)r * 64 + lane];
    *(ushort2*)&xt[w][2 * lane]       = make_ushort2(f2bf(h.x), f2bf(h.y));
    *(ushort2*)&xt[w][128 + 2 * lane] = make_ushort2(f2bf(g.x + accx * inv),
                                                     f2bf(g.y + accy * inv));
    __syncthreads();

    // ---- phase 2: 16x128 GEMM tile, K=256 (waves 0..3 only) ----
    if (w < 4) {
        int lr = lane & 15, lg = lane >> 4;
        const bf16x8* B0 = reinterpret_cast<const bf16x8*>(WT + (size_t)(w * 32 + lr) * KK2 + lg * 8);
        const bf16x8* B1 = reinterpret_cast<const bf16x8*>(WT + (size_t)(w * 32 + 16 + lr) * KK2 + lg * 8);

        f32x4 acc0 = {0.f, 0.f, 0.f, 0.f};
        f32x4 acc1 = {0.f, 0.f, 0.f, 0.f};
#pragma unroll
        for (int kk = 0; kk < 8; ++kk) {
            bf16x8 av = *reinterpret_cast<const bf16x8*>(&xt[lr][lg * 8 + kk * 32]);
            acc0 = __builtin_amdgcn_mfma_f32_16x16x32_bf16(av, B0[kk * 4], acc0, 0, 0, 0);
            acc1 = __builtin_amdgcn_mfma_f32_16x16x32_bf16(av, B1[kk * 4], acc1, 0, 0, 0);
        }

        int col0 = w * 32 + lr;
        int col1 = col0 + 16;
        float bi0 = bias[col0], bi1 = bias[col1];
        int rowb = r0 + lg * 4;
#pragma unroll
        for (int j = 0; j < 4; ++j) {
            float v0 = acc0[j] + bi0;
            float v1 = acc1[j] + bi1;
            out[(size_t)(rowb + j) * DOUT + col0] = v0 > 0.f ? v0 : 0.f;
            out[(size_t)(rowb + j) * DOUT + col1] = v1 > 0.f ? v1 : 0.f;
        }
    }
}

extern "C" void kernel_launch(void* const* d_in, const int* in_sizes, int n_in,
                              void* d_out, int out_size, void* d_ws, size_t ws_size,
                              hipStream_t stream) {
    const float* H_src    = (const float*)d_in[0];
    const float* H_dst    = (const float*)d_in[1];
    const float* HBar_src = (const float*)d_in[2];
    const float* agg      = (const float*)d_in[3];
    const float* W        = (const float*)d_in[4];
    const float* bias     = (const float*)d_in[5];
    const int*   src      = (const int*)d_in[6];
    const int*   dst      = (const int*)d_in[7];
    float* out = (float*)d_out;
    const int E = in_sizes[6];
    const int NB = (NDST + 255) / 256;   // 196

    // ws layout (byte offsets, 512-aligned):
    //   cnt    : 0         .. 200,000
    //   cnt2   : 200,192   .. 400,192
    //   off    : 400,384   .. 600,388   (NDST+1)
    //   bsum   : 600,576   .. 601,360   (196 i32)
    //   idx    : 602,624   .. 3,802,624 (E i32)
    //   WT     : 3,803,136 .. 3,868,672 (128*256 bf16)
    //   hd8    : 3,868,672 .. 16,668,672 (NSRC*128 fp8)
    char* ws = (char*)d_ws;
    int* cnt             = (int*)ws;
    int* cnt2            = (int*)(ws + 200192);
    int* off             = (int*)(ws + 400384);
    int* bsum            = (int*)(ws + 600576);
    int* idx_sorted      = (int*)(ws + 602624);
    unsigned short* WT   = (unsigned short*)(ws + 3803136);
    unsigned short* hd8  = (unsigned short*)(ws + 3868672);

    k_prep<<<NB, 256, 0, stream>>>(W, WT, cnt, cnt2);

    int n8 = NSRC * 16;   // threads, 8 elems each
    k_hd_hist<<<(n8 + 255) / 256, 256, 0, stream>>>(
        (const float4*)H_src, (const float4*)HBar_src, (uint2*)hd8,
        dst, cnt, E, n8);

    k_scan1<<<NB, 256, 0, stream>>>(cnt, bsum, NDST);
    k_scan23<<<NB, 256, 0, stream>>>(cnt, bsum, off, NDST, NB, E);

    k_scatter<<<(E + 255) / 256, 256, 0, stream>>>(src, dst, off, cnt2, idx_sorted, E);

    k_fused<<<NDST / 16, 1024, 0, stream>>>(
        hd8, (const float2*)H_dst, (const float2*)agg,
        off, idx_sorted, WT, bias, out);
}

// Round 10
// 157.249 us; speedup vs baseline: 1.1929x; 1.0341x over previous
//
#include <hip/hip_runtime.h>
#include <hip/hip_bf16.h>
#include <cstdint>
#include <cstddef>

#define NSRC 100000
#define NDST 50000
#define DOUT 128
#define KK2 256   // 2*D

typedef __attribute__((ext_vector_type(8))) short bf16x8;
typedef __attribute__((ext_vector_type(4))) float f32x4;
typedef __attribute__((ext_vector_type(2))) float f32x2;

static __device__ __forceinline__ unsigned short f2bf(float f) {
    union { float f; uint32_t u; } v; v.f = f;
    uint32_t u = v.u;
    uint32_t r = u + 0x7FFFu + ((u >> 16) & 1u);   // round-to-nearest-even
    return (unsigned short)(r >> 16);
}

// ---------------- K1: prep — WT bf16 convert + zero counters ----------------
__global__ __launch_bounds__(256) void k_prep(const float* __restrict__ W,
                                              unsigned short* __restrict__ WT,
                                              int* __restrict__ cnt,
                                              int* __restrict__ cnt2) {
    int i = blockIdx.x * 256 + threadIdx.x;
    if (i < DOUT * KK2) {
        int n = i >> 8;    // output col
        int k = i & 255;   // k index
        WT[i] = f2bf(W[k * DOUT + n]);
    }
    if (i < NDST) { cnt[i] = 0; cnt2[i] = 0; }
}

// ---------------- K2: hdelta_fp8 = e4m3(H_src - HBar_src), fused dst histogram ----------------
// thread i handles 8 elements (two float4 pairs -> uint2 of 8 fp8)
__global__ __launch_bounds__(256) void k_hd_hist(const float4* __restrict__ a,
                                                 const float4* __restrict__ b,
                                                 uint2* __restrict__ o,
                                                 const int* __restrict__ dst,
                                                 int* __restrict__ cnt,
                                                 int E, int n8) {
    int i = blockIdx.x * 256 + threadIdx.x;
    if (i < E) atomicAdd(&cnt[dst[i]], 1);   // fire-and-forget
    if (i < n8) {
        float4 x0 = a[i * 2],     y0 = b[i * 2];
        float4 x1 = a[i * 2 + 1], y1 = b[i * 2 + 1];
        uint32_t p0 = __builtin_amdgcn_cvt_pk_fp8_f32(x0.x - y0.x, x0.y - y0.y, 0u, false);
        p0 = __builtin_amdgcn_cvt_pk_fp8_f32(x0.z - y0.z, x0.w - y0.w, p0, true);
        uint32_t p1 = __builtin_amdgcn_cvt_pk_fp8_f32(x1.x - y1.x, x1.y - y1.y, 0u, false);
        p1 = __builtin_amdgcn_cvt_pk_fp8_f32(x1.z - y1.z, x1.w - y1.w, p1, true);
        o[i] = make_uint2(p0, p1);
    }
}

// ---------------- K3a: per-block sums ----------------
__global__ __launch_bounds__(256) void k_scan1(const int* __restrict__ cnt,
                                               int* __restrict__ bsum, int n) {
    int i = blockIdx.x * 256 + threadIdx.x;
    int v = (i < n) ? cnt[i] : 0;
#pragma unroll
    for (int s = 1; s < 64; s <<= 1) v += __shfl_xor(v, s, 64);
    __shared__ int wsum[4];
    if ((threadIdx.x & 63) == 0) wsum[threadIdx.x >> 6] = v;
    __syncthreads();
    if (threadIdx.x == 0) bsum[blockIdx.x] = wsum[0] + wsum[1] + wsum[2] + wsum[3];
}

// ---------------- K3b: merged scan — each block derives its own base from bsum,
//                  then scans its 256 cnt values and writes off ----------------
__global__ __launch_bounds__(256) void k_scan23(const int* __restrict__ cnt,
                                                const int* __restrict__ bsum,
                                                int* __restrict__ off,
                                                int n, int nb, int E) {
    __shared__ int wsum[4], wex[4];
    __shared__ int base_s;
    int t = threadIdx.x;
    int lane = t & 63, w = t >> 6;

    // phase A: scan the (nb<=256) block sums; pick out exclusive value at blockIdx.x
    int bv = (t < nb) ? bsum[t] : 0;
    int x = bv;
#pragma unroll
    for (int s = 1; s < 64; s <<= 1) { int tt = __shfl_up(x, s, 64); if (lane >= s) x += tt; }
    if (lane == 63) wsum[w] = x;
    __syncthreads();
    if (t == 0) {
        int run = 0;
#pragma unroll
        for (int k = 0; k < 4; ++k) { wex[k] = run; run += wsum[k]; }
    }
    __syncthreads();
    if (t == (int)blockIdx.x) base_s = wex[w] + x - bv;   // exclusive sum of bsum[0..blockIdx)
    __syncthreads();
    int base = base_s;
    __syncthreads();   // protect wsum/wex reuse

    // phase B: scan this block's cnt slice
    int i = blockIdx.x * 256 + t;
    int v = (i < n) ? cnt[i] : 0;
    x = v;
#pragma unroll
    for (int s = 1; s < 64; s <<= 1) { int tt = __shfl_up(x, s, 64); if (lane >= s) x += tt; }
    if (lane == 63) wsum[w] = x;
    __syncthreads();
    if (t == 0) {
        int run = 0;
#pragma unroll
        for (int k = 0; k < 4; ++k) { wex[k] = run; run += wsum[k]; }
    }
    __syncthreads();
    if (i < n) off[i] = base + wex[w] + x - v;
    if (blockIdx.x == 0 && t == 0) off[n] = E;
}

// ---------------- K4: scatter src ids into dst-sorted buckets ----------------
__global__ void k_scatter(const int* __restrict__ src, const int* __restrict__ dst,
                          const int* __restrict__ off, int* __restrict__ cur,
                          int* __restrict__ idx, int E) {
    int e = blockIdx.x * blockDim.x + threadIdx.x;
    if (e < E) {
        int d = dst[e];
        int p = off[d] + atomicAdd(&cur[d], 1);
        idx[p] = src[e];
    }
}

// ---------------- K5: barrier-free gather-mean-agg -> Xn (h_neigh, bf16) ----------------
// 4 waves/block, ONE dst row per wave, NO barrier — waves retire independently so
// degree stragglers are absorbed by occupancy. fp8 table: lane owns cols 2l,2l+1
// (one ushort = 2 fp8). Lane-parallel idx prefetch + shfl broadcast; unroll-8 =>
// 8 independent 128B row-gathers in flight. No min-wave bound: VGPRs free for
// compiler software-pipelining of gather rounds.
__global__ __launch_bounds__(256) void k_gath(const unsigned short* __restrict__ hd8,
                                              const float2* __restrict__ agg,
                                              const int* __restrict__ off,
                                              const int* __restrict__ idx,
                                              ushort2* __restrict__ Xn, int n) {
    int r = blockIdx.x * 4 + (threadIdx.x >> 6);
    if (r >= n) return;
    int lane = threadIdx.x & 63;
    int o0 = off[r], o1 = off[r + 1];
    float accx = 0.f, accy = 0.f;
    for (int c = o0; c < o1; c += 64) {
        int m = o1 - c; if (m > 64) m = 64;
        int myi = (lane < m) ? idx[c + lane] : 0;
        int jm = m & ~7;
        for (int j = 0; j < jm; j += 8) {
            int s0 = __shfl(myi, j + 0), s1 = __shfl(myi, j + 1);
            int s2 = __shfl(myi, j + 2), s3 = __shfl(myi, j + 3);
            int s4 = __shfl(myi, j + 4), s5 = __shfl(myi, j + 5);
            int s6 = __shfl(myi, j + 6), s7 = __shfl(myi, j + 7);
            unsigned int u0 = hd8[(size_t)s0 * 64 + lane];
            unsigned int u1 = hd8[(size_t)s1 * 64 + lane];
            unsigned int u2 = hd8[(size_t)s2 * 64 + lane];
            unsigned int u3 = hd8[(size_t)s3 * 64 + lane];
            unsigned int u4 = hd8[(size_t)s4 * 64 + lane];
            unsigned int u5 = hd8[(size_t)s5 * 64 + lane];
            unsigned int u6 = hd8[(size_t)s6 * 64 + lane];
            unsigned int u7 = hd8[(size_t)s7 * 64 + lane];
            f32x2 d0 = __builtin_amdgcn_cvt_pk_f32_fp8(u0, false);
            f32x2 d1 = __builtin_amdgcn_cvt_pk_f32_fp8(u1, false);
            f32x2 d2 = __builtin_amdgcn_cvt_pk_f32_fp8(u2, false);
            f32x2 d3 = __builtin_amdgcn_cvt_pk_f32_fp8(u3, false);
            f32x2 d4 = __builtin_amdgcn_cvt_pk_f32_fp8(u4, false);
            f32x2 d5 = __builtin_amdgcn_cvt_pk_f32_fp8(u5, false);
            f32x2 d6 = __builtin_amdgcn_cvt_pk_f32_fp8(u6, false);
            f32x2 d7 = __builtin_amdgcn_cvt_pk_f32_fp8(u7, false);
            accx += d0[0] + d1[0] + d2[0] + d3[0] + d4[0] + d5[0] + d6[0] + d7[0];
            accy += d0[1] + d1[1] + d2[1] + d3[1] + d4[1] + d5[1] + d6[1] + d7[1];
        }
        for (int j = jm; j < m; ++j) {
            int s = __shfl(myi, j);
            unsigned int u = hd8[(size_t)s * 64 + lane];
            f32x2 d = __builtin_amdgcn_cvt_pk_f32_fp8(u, false);
            accx += d[0];
            accy += d[1];
        }
    }
    float inv = 1.0f / fmaxf((float)(o1 - o0), 1.0f);
    float2 g = agg[(size_t)r * 64 + lane];
    Xn[(size_t)r * 64 + lane] = make_ushort2(f2bf(g.x + accx * inv),
                                             f2bf(g.y + accy * inv));
}

// ---------------- K6: GEMM [NDST,256] x [256,128] + bias + relu, LDS-staged A ----------------
// block = 256 thr = 4 waves, one 16-row M-tile. Stage: thread t loads 8 f32 of
// H_dst (coalesced 32B) -> bf16 and 8 bf16 of Xn (coalesced 16B) into the x-tile.
// Then round-9's MFMA phase on all 4 waves (wave w -> cols [w*32, w*32+32)).
__global__ __launch_bounds__(256) void k_gemm(const float4* __restrict__ Hd4,
                                              const unsigned short* __restrict__ Xn,
                                              const unsigned short* __restrict__ WT,
                                              const float* __restrict__ bias,
                                              float* __restrict__ out) {
    __shared__ __align__(16) unsigned short xt[16][264];
    int r0 = blockIdx.x * 16;
    int t = threadIdx.x;

    // ---- stage A-tile ----
    {
        int row = t >> 4, col8 = (t & 15) * 8;
        const float4* hrow = Hd4 + (size_t)(r0 + row) * 32 + (col8 >> 2);
        float4 p = hrow[0], q = hrow[1];
        bf16x8 hv;
        hv[0] = (short)f2bf(p.x); hv[1] = (short)f2bf(p.y);
        hv[2] = (short)f2bf(p.z); hv[3] = (short)f2bf(p.w);
        hv[4] = (short)f2bf(q.x); hv[5] = (short)f2bf(q.y);
        hv[6] = (short)f2bf(q.z); hv[7] = (short)f2bf(q.w);
        *(bf16x8*)&xt[row][col8] = hv;
        bf16x8 xv = *reinterpret_cast<const bf16x8*>(Xn + (size_t)(r0 + row) * 128 + col8);
        *(bf16x8*)&xt[row][128 + col8] = xv;
    }
    __syncthreads();

    // ---- MFMA phase ----
    int w = t >> 6, lane = t & 63;
    int lr = lane & 15, lg = lane >> 4;
    const bf16x8* B0 = reinterpret_cast<const bf16x8*>(WT + (size_t)(w * 32 + lr) * KK2 + lg * 8);
    const bf16x8* B1 = reinterpret_cast<const bf16x8*>(WT + (size_t)(w * 32 + 16 + lr) * KK2 + lg * 8);

    f32x4 acc0 = {0.f, 0.f, 0.f, 0.f};
    f32x4 acc1 = {0.f, 0.f, 0.f, 0.f};
#pragma unroll
    for (int kk = 0; kk < 8; ++kk) {
        bf16x8 av = *reinterpret_cast<const bf16x8*>(&xt[lr][lg * 8 + kk * 32]);
        acc0 = __builtin_amdgcn_mfma_f32_16x16x32_bf16(av, B0[kk * 4], acc0, 0, 0, 0);
        acc1 = __builtin_amdgcn_mfma_f32_16x16x32_bf16(av, B1[kk * 4], acc1, 0, 0, 0);
    }

    int col0 = w * 32 + lr;
    int col1 = col0 + 16;
    float bi0 = bias[col0], bi1 = bias[col1];
    int rowb = r0 + lg * 4;
#pragma unroll
    for (int j = 0; j < 4; ++j) {
        float v0 = acc0[j] + bi0;
        float v1 = acc1[j] + bi1;
        out[(size_t)(rowb + j) * DOUT + col0] = v0 > 0.f ? v0 : 0.f;
        out[(size_t)(rowb + j) * DOUT + col1] = v1 > 0.f ? v1 : 0.f;
    }
}

extern "C" void kernel_launch(void* const* d_in, const int* in_sizes, int n_in,
                              void* d_out, int out_size, void* d_ws, size_t ws_size,
                              hipStream_t stream) {
    const float* H_src    = (const float*)d_in[0];
    const float* H_dst    = (const float*)d_in[1];
    const float* HBar_src = (const float*)d_in[2];
    const float* agg      = (const float*)d_in[3];
    const float* W        = (const float*)d_in[4];
    const float* bias     = (const float*)d_in[5];
    const int*   src      = (const int*)d_in[6];
    const int*   dst      = (const int*)d_in[7];
    float* out = (float*)d_out;
    const int E = in_sizes[6];
    const int NB = (NDST + 255) / 256;   // 196

    // ws layout (byte offsets, 512-aligned):
    //   cnt    : 0          .. 200,000
    //   cnt2   : 200,192    .. 400,192
    //   off    : 400,384    .. 600,388   (NDST+1)
    //   bsum   : 600,576    .. 601,360   (196 i32)
    //   idx    : 602,624    .. 3,802,624 (E i32)
    //   WT     : 3,803,136  .. 3,868,672 (128*256 bf16)
    //   hd8    : 3,868,672  .. 16,668,672 (NSRC*128 fp8)
    //   Xn     : 16,668,672 .. 29,468,672 (NDST*128 bf16)
    char* ws = (char*)d_ws;
    int* cnt             = (int*)ws;
    int* cnt2            = (int*)(ws + 200192);
    int* off             = (int*)(ws + 400384);
    int* bsum            = (int*)(ws + 600576);
    int* idx_sorted      = (int*)(ws + 602624);
    unsigned short* WT   = (unsigned short*)(ws + 3803136);
    unsigned short* hd8  = (unsigned short*)(ws + 3868672);
    unsigned short* Xn   = (unsigned short*)(ws + 16668672);

    k_prep<<<NB, 256, 0, stream>>>(W, WT, cnt, cnt2);

    int n8 = NSRC * 16;   // threads, 8 elems each
    k_hd_hist<<<(n8 + 255) / 256, 256, 0, stream>>>(
        (const float4*)H_src, (const float4*)HBar_src, (uint2*)hd8,
        dst, cnt, E, n8);

    k_scan1<<<NB, 256, 0, stream>>>(cnt, bsum, NDST);
    k_scan23<<<NB, 256, 0, stream>>>(cnt, bsum, off, NDST, NB, E);

    k_scatter<<<(E + 255) / 256, 256, 0, stream>>>(src, dst, off, cnt2, idx_sorted, E);

    k_gath<<<(NDST + 3) / 4, 256, 0, stream>>>(
        hd8, (const float2*)agg, off, idx_sorted, (ushort2*)Xn, NDST);

    k_gemm<<<NDST / 16, 256, 0, stream>>>(
        (const float4*)H_dst, Xn, WT, bias, out);
}

// Round 11
// 126.620 us; speedup vs baseline: 1.4815x; 1.2419x over previous
//
#include <hip/hip_runtime.h>
#include <hip/hip_bf16.h>
#include <cstdint>
#include <cstddef>

#define NSRC 100000
#define NDST 50000
#define DOUT 128
#define KK2 256    // 2*D
#define NBUCK 196  // ceil(NDST/256) buckets of 256 dst each
#define CHUNK 4096 // edges per block in binning passes

typedef __attribute__((ext_vector_type(8))) short bf16x8;
typedef __attribute__((ext_vector_type(4))) float f32x4;
typedef __attribute__((ext_vector_type(2))) float f32x2;

static __device__ __forceinline__ unsigned short f2bf(float f) {
    union { float f; uint32_t u; } v; v.f = f;
    uint32_t u = v.u;
    uint32_t r = u + 0x7FFFu + ((u >> 16) & 1u);   // round-to-nearest-even
    return (unsigned short)(r >> 16);
}

// ---------------- K1: prep — WT bf16 convert + zero bucket counters ----------------
__global__ __launch_bounds__(256) void k_prep(const float* __restrict__ W,
                                              unsigned short* __restrict__ WT,
                                              int* __restrict__ bcnt) {
    int i = blockIdx.x * 256 + threadIdx.x;
    if (i < DOUT * KK2) {
        int n = i >> 8;    // output col
        int k = i & 255;   // k index
        WT[i] = f2bf(W[k * DOUT + n]);
    }
    if (i < 256) bcnt[i] = 0;
}

// ---------------- K2: hdelta_fp8 = e4m3(H_src - HBar_src), PURE STREAM ----------------
__global__ __launch_bounds__(256) void k_hdelta(const float4* __restrict__ a,
                                                const float4* __restrict__ b,
                                                uint2* __restrict__ o, int n8) {
    int i = blockIdx.x * 256 + threadIdx.x;
    if (i < n8) {
        float4 x0 = a[i * 2],     y0 = b[i * 2];
        float4 x1 = a[i * 2 + 1], y1 = b[i * 2 + 1];
        uint32_t p0 = __builtin_amdgcn_cvt_pk_fp8_f32(x0.x - y0.x, x0.y - y0.y, 0u, false);
        p0 = __builtin_amdgcn_cvt_pk_fp8_f32(x0.z - y0.z, x0.w - y0.w, p0, true);
        uint32_t p1 = __builtin_amdgcn_cvt_pk_fp8_f32(x1.x - y1.x, x1.y - y1.y, 0u, false);
        p1 = __builtin_amdgcn_cvt_pk_fp8_f32(x1.z - y1.z, x1.w - y1.w, p1, true);
        o[i] = make_uint2(p0, p1);
    }
}

// ---------------- K3: bucket histogram (LDS-aggregated; 196 coarse buckets) ----------------
__global__ __launch_bounds__(256) void k_binA1(const int* __restrict__ dst,
                                               int* __restrict__ bcnt, int E) {
    __shared__ int bh[NBUCK];
    int t = threadIdx.x;
    if (t < NBUCK) bh[t] = 0;
    __syncthreads();
    int base = blockIdx.x * CHUNK;
    for (int i = t; i < CHUNK; i += 256) {
        int e = base + i;
        if (e < E) atomicAdd(&bh[dst[e] >> 8], 1);
    }
    __syncthreads();
    if (t < NBUCK && bh[t]) atomicAdd(&bcnt[t], bh[t]);
}

// ---------------- K4: 196-bucket exclusive scan -> bbase, bcur; off[NDST]=E ----------------
__global__ __launch_bounds__(256) void k_scanB(const int* __restrict__ bcnt,
                                               int* __restrict__ bbase,
                                               int* __restrict__ bcur,
                                               int* __restrict__ off, int E) {
    int t = threadIdx.x;
    int v = (t < NBUCK) ? bcnt[t] : 0;
    int lane = t & 63, w = t >> 6;
    int x = v;
#pragma unroll
    for (int s = 1; s < 64; s <<= 1) { int tt = __shfl_up(x, s, 64); if (lane >= s) x += tt; }
    __shared__ int wsum[4], wex[4];
    if (lane == 63) wsum[w] = x;
    __syncthreads();
    if (t == 0) {
        int run = 0;
#pragma unroll
        for (int k = 0; k < 4; ++k) { wex[k] = run; run += wsum[k]; }
    }
    __syncthreads();
    int ex = wex[w] + x - v;
    if (t < NBUCK) { bbase[t] = ex; bcur[t] = ex; }
    if (t == 0) off[NDST] = E;
}

// ---------------- K5: bin edges into bucket regions as packed (dlow<<24)|src ----------------
__global__ __launch_bounds__(256) void k_binA2(const int* __restrict__ src,
                                               const int* __restrict__ dst,
                                               int* __restrict__ bcur,
                                               uint32_t* __restrict__ pairs, int E) {
    __shared__ int bh[NBUCK];
    __shared__ int lcur[NBUCK];
    int t = threadIdx.x;
    if (t < NBUCK) bh[t] = 0;
    __syncthreads();
    int base = blockIdx.x * CHUNK;
    for (int i = t; i < CHUNK; i += 256) {
        int e = base + i;
        if (e < E) atomicAdd(&bh[dst[e] >> 8], 1);
    }
    __syncthreads();
    if (t < NBUCK) lcur[t] = bh[t] ? atomicAdd(&bcur[t], bh[t]) : 0;
    __syncthreads();
    for (int i = t; i < CHUNK; i += 256) {
        int e = base + i;
        if (e < E) {
            int d = dst[e];
            int pos = atomicAdd(&lcur[d >> 8], 1);
            pairs[pos] = ((uint32_t)(d & 255) << 24) | (uint32_t)src[e];
        }
    }
}

// ---------------- K6: per-bucket local sort: off[] + idx[] (coalesced region writes) ----------------
__global__ __launch_bounds__(256) void k_binB(const uint32_t* __restrict__ pairs,
                                              const int* __restrict__ bcnt,
                                              const int* __restrict__ bbase,
                                              int* __restrict__ off,
                                              int* __restrict__ idx) {
    __shared__ int lcnt[256];
    __shared__ int lcur[256];
    __shared__ int wsum[4], wex[4];
    int b = blockIdx.x, t = threadIdx.x;
    int cnt = bcnt[b], gbase = bbase[b];
    lcnt[t] = 0;
    __syncthreads();
    for (int i = t; i < cnt; i += 256)
        atomicAdd(&lcnt[pairs[gbase + i] >> 24], 1);
    __syncthreads();
    // block-wide exclusive scan of lcnt
    int v = lcnt[t];
    int lane = t & 63, w = t >> 6;
    int x = v;
#pragma unroll
    for (int s = 1; s < 64; s <<= 1) { int tt = __shfl_up(x, s, 64); if (lane >= s) x += tt; }
    if (lane == 63) wsum[w] = x;
    __syncthreads();
    if (t == 0) {
        int run = 0;
#pragma unroll
        for (int k = 0; k < 4; ++k) { wex[k] = run; run += wsum[k]; }
    }
    __syncthreads();
    int ex = wex[w] + x - v;
    lcur[t] = ex;
    int d = b * 256 + t;
    if (d < NDST) off[d] = gbase + ex;
    __syncthreads();
    for (int i = t; i < cnt; i += 256) {
        uint32_t p = pairs[gbase + i];
        int pos = atomicAdd(&lcur[p >> 24], 1);
        idx[gbase + pos] = (int)(p & 0xFFFFFFu);
    }
}

// ---------------- K7: barrier-free gather-mean-agg -> Xn (h_neigh, bf16) ----------------
// 4 waves/block, ONE dst row per wave, no barrier. fp8 table: lane owns cols
// 2l,2l+1 (one ushort = 2 fp8). Lane-parallel idx prefetch + shfl broadcast;
// unroll-8 => 8 independent 128B row-gathers in flight.
__global__ __launch_bounds__(256) void k_gath(const unsigned short* __restrict__ hd8,
                                              const float2* __restrict__ agg,
                                              const int* __restrict__ off,
                                              const int* __restrict__ idx,
                                              ushort2* __restrict__ Xn, int n) {
    int r = blockIdx.x * 4 + (threadIdx.x >> 6);
    if (r >= n) return;
    int lane = threadIdx.x & 63;
    int o0 = off[r], o1 = off[r + 1];
    float accx = 0.f, accy = 0.f;
    for (int c = o0; c < o1; c += 64) {
        int m = o1 - c; if (m > 64) m = 64;
        int myi = (lane < m) ? idx[c + lane] : 0;
        int jm = m & ~7;
        for (int j = 0; j < jm; j += 8) {
            int s0 = __shfl(myi, j + 0), s1 = __shfl(myi, j + 1);
            int s2 = __shfl(myi, j + 2), s3 = __shfl(myi, j + 3);
            int s4 = __shfl(myi, j + 4), s5 = __shfl(myi, j + 5);
            int s6 = __shfl(myi, j + 6), s7 = __shfl(myi, j + 7);
            unsigned int u0 = hd8[(size_t)s0 * 64 + lane];
            unsigned int u1 = hd8[(size_t)s1 * 64 + lane];
            unsigned int u2 = hd8[(size_t)s2 * 64 + lane];
            unsigned int u3 = hd8[(size_t)s3 * 64 + lane];
            unsigned int u4 = hd8[(size_t)s4 * 64 + lane];
            unsigned int u5 = hd8[(size_t)s5 * 64 + lane];
            unsigned int u6 = hd8[(size_t)s6 * 64 + lane];
            unsigned int u7 = hd8[(size_t)s7 * 64 + lane];
            f32x2 d0 = __builtin_amdgcn_cvt_pk_f32_fp8(u0, false);
            f32x2 d1 = __builtin_amdgcn_cvt_pk_f32_fp8(u1, false);
            f32x2 d2 = __builtin_amdgcn_cvt_pk_f32_fp8(u2, false);
            f32x2 d3 = __builtin_amdgcn_cvt_pk_f32_fp8(u3, false);
            f32x2 d4 = __builtin_amdgcn_cvt_pk_f32_fp8(u4, false);
            f32x2 d5 = __builtin_amdgcn_cvt_pk_f32_fp8(u5, false);
            f32x2 d6 = __builtin_amdgcn_cvt_pk_f32_fp8(u6, false);
            f32x2 d7 = __builtin_amdgcn_cvt_pk_f32_fp8(u7, false);
            accx += d0[0] + d1[0] + d2[0] + d3[0] + d4[0] + d5[0] + d6[0] + d7[0];
            accy += d0[1] + d1[1] + d2[1] + d3[1] + d4[1] + d5[1] + d6[1] + d7[1];
        }
        for (int j = jm; j < m; ++j) {
            int s = __shfl(myi, j);
            unsigned int u = hd8[(size_t)s * 64 + lane];
            f32x2 d = __builtin_amdgcn_cvt_pk_f32_fp8(u, false);
            accx += d[0];
            accy += d[1];
        }
    }
    float inv = 1.0f / fmaxf((float)(o1 - o0), 1.0f);
    float2 g = agg[(size_t)r * 64 + lane];
    Xn[(size_t)r * 64 + lane] = make_ushort2(f2bf(g.x + accx * inv),
                                             f2bf(g.y + accy * inv));
}

// ---------------- K8: GEMM [NDST,256] x [256,128] + bias + relu, LDS-staged A ----------------
__global__ __launch_bounds__(256) void k_gemm(const float4* __restrict__ Hd4,
                                              const unsigned short* __restrict__ Xn,
                                              const unsigned short* __restrict__ WT,
                                              const float* __restrict__ bias,
                                              float* __restrict__ out) {
    __shared__ __align__(16) unsigned short xt[16][264];
    int r0 = blockIdx.x * 16;
    int t = threadIdx.x;

    // ---- stage A-tile ----
    {
        int row = t >> 4, col8 = (t & 15) * 8;
        const float4* hrow = Hd4 + (size_t)(r0 + row) * 32 + (col8 >> 2);
        float4 p = hrow[0], q = hrow[1];
        bf16x8 hv;
        hv[0] = (short)f2bf(p.x); hv[1] = (short)f2bf(p.y);
        hv[2] = (short)f2bf(p.z); hv[3] = (short)f2bf(p.w);
        hv[4] = (short)f2bf(q.x); hv[5] = (short)f2bf(q.y);
        hv[6] = (short)f2bf(q.z); hv[7] = (short)f2bf(q.w);
        *(bf16x8*)&xt[row][col8] = hv;
        bf16x8 xv = *reinterpret_cast<const bf16x8*>(Xn + (size_t)(r0 + row) * 128 + col8);
        *(bf16x8*)&xt[row][128 + col8] = xv;
    }
    __syncthreads();

    // ---- MFMA phase ----
    int w = t >> 6, lane = t & 63;
    int lr = lane & 15, lg = lane >> 4;
    const bf16x8* B0 = reinterpret_cast<const bf16x8*>(WT + (size_t)(w * 32 + lr) * KK2 + lg * 8);
    const bf16x8* B1 = reinterpret_cast<const bf16x8*>(WT + (size_t)(w * 32 + 16 + lr) * KK2 + lg * 8);

    f32x4 acc0 = {0.f, 0.f, 0.f, 0.f};
    f32x4 acc1 = {0.f, 0.f, 0.f, 0.f};
#pragma unroll
    for (int kk = 0; kk < 8; ++kk) {
        bf16x8 av = *reinterpret_cast<const bf16x8*>(&xt[lr][lg * 8 + kk * 32]);
        acc0 = __builtin_amdgcn_mfma_f32_16x16x32_bf16(av, B0[kk * 4], acc0, 0, 0, 0);
        acc1 = __builtin_amdgcn_mfma_f32_16x16x32_bf16(av, B1[kk * 4], acc1, 0, 0, 0);
    }

    int col0 = w * 32 + lr;
    int col1 = col0 + 16;
    float bi0 = bias[col0], bi1 = bias[col1];
    int rowb = r0 + lg * 4;
#pragma unroll
    for (int j = 0; j < 4; ++j) {
        float v0 = acc0[j] + bi0;
        float v1 = acc1[j] + bi1;
        out[(size_t)(rowb + j) * DOUT + col0] = v0 > 0.f ? v0 : 0.f;
        out[(size_t)(rowb + j) * DOUT + col1] = v1 > 0.f ? v1 : 0.f;
    }
}

extern "C" void kernel_launch(void* const* d_in, const int* in_sizes, int n_in,
                              void* d_out, int out_size, void* d_ws, size_t ws_size,
                              hipStream_t stream) {
    const float* H_src    = (const float*)d_in[0];
    const float* H_dst    = (const float*)d_in[1];
    const float* HBar_src = (const float*)d_in[2];
    const float* agg      = (const float*)d_in[3];
    const float* W        = (const float*)d_in[4];
    const float* bias     = (const float*)d_in[5];
    const int*   src      = (const int*)d_in[6];
    const int*   dst      = (const int*)d_in[7];
    float* out = (float*)d_out;
    const int E = in_sizes[6];

    // ws layout (byte offsets):
    //   bcnt   : 0          .. 1,024      (256 i32, zeroed in prep)
    //   bbase  : 1,024      .. 2,048
    //   bcur   : 2,048      .. 3,072
    //   off    : 3,072      .. 203,076    (NDST+1 i32)
    //   pairs  : 203,264    .. 3,403,264  (E u32)
    //   idx    : 3,403,264  .. 6,603,264  (E i32)
    //   WT     : 6,603,264  .. 6,668,800  (128*256 bf16)
    //   hd8    : 6,668,800  .. 19,468,800 (NSRC*128 fp8)
    //   Xn     : 19,468,800 .. 32,268,800 (NDST*128 bf16)
    char* ws = (char*)d_ws;
    int* bcnt            = (int*)ws;
    int* bbase           = (int*)(ws + 1024);
    int* bcur            = (int*)(ws + 2048);
    int* off             = (int*)(ws + 3072);
    uint32_t* pairs      = (uint32_t*)(ws + 203264);
    int* idx_sorted      = (int*)(ws + 3403264);
    unsigned short* WT   = (unsigned short*)(ws + 6603264);
    unsigned short* hd8  = (unsigned short*)(ws + 6668800);
    unsigned short* Xn   = (unsigned short*)(ws + 19468800);

    const int NBE = (E + CHUNK - 1) / CHUNK;   // 196 binning blocks

    k_prep<<<128, 256, 0, stream>>>(W, WT, bcnt);

    int n8 = NSRC * 16;   // threads, 8 elems each
    k_hdelta<<<(n8 + 255) / 256, 256, 0, stream>>>(
        (const float4*)H_src, (const float4*)HBar_src, (uint2*)hd8, n8);

    k_binA1<<<NBE, 256, 0, stream>>>(dst, bcnt, E);
    k_scanB<<<1, 256, 0, stream>>>(bcnt, bbase, bcur, off, E);
    k_binA2<<<NBE, 256, 0, stream>>>(src, dst, bcur, pairs, E);
    k_binB<<<NBUCK, 256, 0, stream>>>(pairs, bcnt, bbase, off, idx_sorted);

    k_gath<<<(NDST + 3) / 4, 256, 0, stream>>>(
        hd8, (const float2*)agg, off, idx_sorted, (ushort2*)Xn, NDST);

    k_gemm<<<NDST / 16, 256, 0, stream>>>(
        (const float4*)H_dst, Xn, WT, bias, out);
}

// Round 13
// 119.360 us; speedup vs baseline: 1.5716x; 1.0608x over previous
//
#include <hip/hip_runtime.h>
#include <hip/hip_bf16.h>
#include <cstdint>
#include <cstddef>

#define NSRC 100000
#define NDST 50000
#define DOUT 128
#define KK2 256    // 2*D
#define NBUCK 196  // ceil(NDST/256) buckets of 256 dst each
#define CHUNK 4096 // edges per block in binning passes

typedef __attribute__((ext_vector_type(8))) short bf16x8;
typedef __attribute__((ext_vector_type(4))) float f32x4;
typedef __attribute__((ext_vector_type(2))) float f32x2;

static __device__ __forceinline__ unsigned short f2bf(float f) {
    union { float f; uint32_t u; } v; v.f = f;
    uint32_t u = v.u;
    uint32_t r = u + 0x7FFFu + ((u >> 16) & 1u);   // round-to-nearest-even
    return (unsigned short)(r >> 16);
}

// ---------------- K1: prep — WT bf16 convert + zero bucket counters ----------------
__global__ __launch_bounds__(256) void k_prep(const float* __restrict__ W,
                                              unsigned short* __restrict__ WT,
                                              int* __restrict__ bcnt,
                                              int* __restrict__ bcur2) {
    int i = blockIdx.x * 256 + threadIdx.x;
    if (i < DOUT * KK2) {
        int n = i >> 8;    // output col
        int k = i & 255;   // k index
        WT[i] = f2bf(W[k * DOUT + n]);
    }
    if (i < 256) { bcnt[i] = 0; bcur2[i] = 0; }
}

// ---------------- K2: fused hdelta_fp8 stream + bucket histogram (role-split) ----------------
// blocks [0, NBE): LDS-aggregated 196-bucket histogram of dst (38K global atomics total)
// blocks [NBE, ...): pure fp8 encode stream, thread handles 8 elems
__global__ __launch_bounds__(256) void k_hd_binA1(const float4* __restrict__ a,
                                                  const float4* __restrict__ b,
                                                  uint2* __restrict__ o, int n8,
                                                  const int* __restrict__ dst,
                                                  int* __restrict__ bcnt,
                                                  int E, int nbe) {
    __shared__ int bh[NBUCK];
    int t = threadIdx.x;
    if ((int)blockIdx.x < nbe) {
        if (t < NBUCK) bh[t] = 0;
        __syncthreads();
        int base = blockIdx.x * CHUNK;
        for (int i = t; i < CHUNK; i += 256) {
            int e = base + i;
            if (e < E) atomicAdd(&bh[dst[e] >> 8], 1);
        }
        __syncthreads();
        if (t < NBUCK && bh[t]) atomicAdd(&bcnt[t], bh[t]);
    } else {
        int i = ((int)blockIdx.x - nbe) * 256 + t;
        if (i < n8) {
            float4 x0 = a[i * 2],     y0 = b[i * 2];
            float4 x1 = a[i * 2 + 1], y1 = b[i * 2 + 1];
            uint32_t p0 = __builtin_amdgcn_cvt_pk_fp8_f32(x0.x - y0.x, x0.y - y0.y, 0u, false);
            p0 = __builtin_amdgcn_cvt_pk_fp8_f32(x0.z - y0.z, x0.w - y0.w, p0, true);
            uint32_t p1 = __builtin_amdgcn_cvt_pk_fp8_f32(x1.x - y1.x, x1.y - y1.y, 0u, false);
            p1 = __builtin_amdgcn_cvt_pk_fp8_f32(x1.z - y1.z, x1.w - y1.w, p1, true);
            o[i] = make_uint2(p0, p1);
        }
    }
}

// ---------------- K3: bin edges into bucket regions (scanB folded in) ----------------
// each block scans the 196-entry bcnt in LDS to get bucket bases, then allocates
// its chunk's share via one global atomic per touched bucket.
__global__ __launch_bounds__(256) void k_binA2(const int* __restrict__ src,
                                               const int* __restrict__ dst,
                                               const int* __restrict__ bcnt,
                                               int* __restrict__ bcur2,
                                               uint32_t* __restrict__ pairs, int E) {
    __shared__ int bh[NBUCK], lcur[NBUCK];
    __shared__ int wsum[4], wex[4];
    int t = threadIdx.x;
    int lane = t & 63, w = t >> 6;

    if (t < NBUCK) bh[t] = 0;
    __syncthreads();
    int base = blockIdx.x * CHUNK;
    for (int i = t; i < CHUNK; i += 256) {
        int e = base + i;
        if (e < E) atomicAdd(&bh[dst[e] >> 8], 1);
    }

    // in-block exclusive scan of bcnt -> bucket base
    int v = (t < NBUCK) ? bcnt[t] : 0;
    int x = v;
#pragma unroll
    for (int s = 1; s < 64; s <<= 1) { int tt = __shfl_up(x, s, 64); if (lane >= s) x += tt; }
    if (lane == 63) wsum[w] = x;
    __syncthreads();
    if (t == 0) {
        int run = 0;
#pragma unroll
        for (int k = 0; k < 4; ++k) { wex[k] = run; run += wsum[k]; }
    }
    __syncthreads();
    int ex = wex[w] + x - v;

    if (t < NBUCK) lcur[t] = bh[t] ? (ex + atomicAdd(&bcur2[t], bh[t])) : 0;
    __syncthreads();

    for (int i = t; i < CHUNK; i += 256) {
        int e = base + i;
        if (e < E) {
            int d = dst[e];
            int pos = atomicAdd(&lcur[d >> 8], 1);
            pairs[pos] = ((uint32_t)(d & 255) << 24) | (uint32_t)src[e];
        }
    }
}

// ---------------- K4: per-bucket local sort: off[] + idx[] (coalesced region writes) ----------------
__global__ __launch_bounds__(256) void k_binB(const uint32_t* __restrict__ pairs,
                                              const int* __restrict__ bcnt,
                                              int* __restrict__ off,
                                              int* __restrict__ idx, int E) {
    __shared__ int lcnt[256];
    __shared__ int lcur[256];
    __shared__ int wsum[4], wex[4];
    __shared__ int gbase_s;
    int b = blockIdx.x, t = threadIdx.x;
    int lane = t & 63, w = t >> 6;

    // in-block exclusive scan of bcnt -> this bucket's base
    int v = (t < NBUCK) ? bcnt[t] : 0;
    int x = v;
#pragma unroll
    for (int s = 1; s < 64; s <<= 1) { int tt = __shfl_up(x, s, 64); if (lane >= s) x += tt; }
    if (lane == 63) wsum[w] = x;
    __syncthreads();
    if (t == 0) {
        int run = 0;
#pragma unroll
        for (int k = 0; k < 4; ++k) { wex[k] = run; run += wsum[k]; }
    }
    __syncthreads();
    if (t == b) gbase_s = wex[w] + x - v;
    lcnt[t] = 0;
    __syncthreads();
    int gbase = gbase_s;
    int cnt = bcnt[b];

    for (int i = t; i < cnt; i += 256)
        atomicAdd(&lcnt[pairs[gbase + i] >> 24], 1);
    __syncthreads();

    // block-wide exclusive scan of lcnt
    v = lcnt[t];
    x = v;
#pragma unroll
    for (int s = 1; s < 64; s <<= 1) { int tt = __shfl_up(x, s, 64); if (lane >= s) x += tt; }
    if (lane == 63) wsum[w] = x;
    __syncthreads();
    if (t == 0) {
        int run = 0;
#pragma unroll
        for (int k = 0; k < 4; ++k) { wex[k] = run; run += wsum[k]; }
    }
    __syncthreads();
    int ex = wex[w] + x - v;
    lcur[t] = ex;
    int d = b * 256 + t;
    if (d < NDST) off[d] = gbase + ex;
    if (b == 0 && t == 0) off[NDST] = E;
    __syncthreads();

    for (int i = t; i < cnt; i += 256) {
        uint32_t p = pairs[gbase + i];
        int pos = atomicAdd(&lcur[p >> 24], 1);
        idx[gbase + pos] = (int)(p & 0xFFFFFFu);
    }
}

// ---------------- K5: barrier-free gather-mean-agg -> Xn (h_neigh, bf16) ----------------
// 4 waves/block, ONE dst row per wave, no barrier. Half-wave gathers: lane owns
// 4 cols (uint = 4 fp8), 32 lanes cover a 128B row; the wave's two halves gather
// TWO edges per instruction round (srcid via one shfl with per-half source lane).
// Unroll-16 => 16 edges (8 uint loads, 2KB) in flight per round. Halves combined
// with shfl_xor(32) at row end.
__global__ __launch_bounds__(256) void k_gath(const uint32_t* __restrict__ hd8u,
                                              const float4* __restrict__ agg4,
                                              const int* __restrict__ off,
                                              const int* __restrict__ idx,
                                              ushort4* __restrict__ Xn, int n) {
    int r = blockIdx.x * 4 + (threadIdx.x >> 6);
    if (r >= n) return;
    int lane = threadIdx.x & 63;
    int li = lane & 31, half = lane >> 5;
    float a0 = 0.f, a1 = 0.f, a2 = 0.f, a3 = 0.f;
    int o0 = off[r], o1 = off[r + 1];
    for (int c = o0; c < o1; c += 64) {
        int m = o1 - c; if (m > 64) m = 64;
        int myi = (lane < m) ? idx[c + lane] : 0;
        int j = 0;
        for (; j + 16 <= m; j += 16) {
            int s0 = __shfl(myi, j + 0 + half);
            int s1 = __shfl(myi, j + 2 + half);
            int s2 = __shfl(myi, j + 4 + half);
            int s3 = __shfl(myi, j + 6 + half);
            int s4 = __shfl(myi, j + 8 + half);
            int s5 = __shfl(myi, j + 10 + half);
            int s6 = __shfl(myi, j + 12 + half);
            int s7 = __shfl(myi, j + 14 + half);
            uint32_t u0 = hd8u[(size_t)s0 * 32 + li];
            uint32_t u1 = hd8u[(size_t)s1 * 32 + li];
            uint32_t u2 = hd8u[(size_t)s2 * 32 + li];
            uint32_t u3 = hd8u[(size_t)s3 * 32 + li];
            uint32_t u4 = hd8u[(size_t)s4 * 32 + li];
            uint32_t u5 = hd8u[(size_t)s5 * 32 + li];
            uint32_t u6 = hd8u[(size_t)s6 * 32 + li];
            uint32_t u7 = hd8u[(size_t)s7 * 32 + li];
            f32x2 l0 = __builtin_amdgcn_cvt_pk_f32_fp8(u0, false);
            f32x2 h0 = __builtin_amdgcn_cvt_pk_f32_fp8(u0, true);
            f32x2 l1 = __builtin_amdgcn_cvt_pk_f32_fp8(u1, false);
            f32x2 h1 = __builtin_amdgcn_cvt_pk_f32_fp8(u1, true);
            f32x2 l2 = __builtin_amdgcn_cvt_pk_f32_fp8(u2, false);
            f32x2 h2 = __builtin_amdgcn_cvt_pk_f32_fp8(u2, true);
            f32x2 l3 = __builtin_amdgcn_cvt_pk_f32_fp8(u3, false);
            f32x2 h3 = __builtin_amdgcn_cvt_pk_f32_fp8(u3, true);
            f32x2 l4 = __builtin_amdgcn_cvt_pk_f32_fp8(u4, false);
            f32x2 h4 = __builtin_amdgcn_cvt_pk_f32_fp8(u4, true);
            f32x2 l5 = __builtin_amdgcn_cvt_pk_f32_fp8(u5, false);
            f32x2 h5 = __builtin_amdgcn_cvt_pk_f32_fp8(u5, true);
            f32x2 l6 = __builtin_amdgcn_cvt_pk_f32_fp8(u6, false);
            f32x2 h6 = __builtin_amdgcn_cvt_pk_f32_fp8(u6, true);
            f32x2 l7 = __builtin_amdgcn_cvt_pk_f32_fp8(u7, false);
            f32x2 h7 = __builtin_amdgcn_cvt_pk_f32_fp8(u7, true);
            a0 += l0[0] + l1[0] + l2[0] + l3[0] + l4[0] + l5[0] + l6[0] + l7[0];
            a1 += l0[1] + l1[1] + l2[1] + l3[1] + l4[1] + l5[1] + l6[1] + l7[1];
            a2 += h0[0] + h1[0] + h2[0] + h3[0] + h4[0] + h5[0] + h6[0] + h7[0];
            a3 += h0[1] + h1[1] + h2[1] + h3[1] + h4[1] + h5[1] + h6[1] + h7[1];
        }
        for (; j < m; j += 2) {
            int tt = j + half;
            int s = __shfl(myi, (tt < m) ? tt : 0);
            uint32_t u = hd8u[(size_t)s * 32 + li];
            if (tt >= m) u = 0;                     // fp8 decode of 0 is 0.0
            f32x2 lo = __builtin_amdgcn_cvt_pk_f32_fp8(u, false);
            f32x2 hi = __builtin_amdgcn_cvt_pk_f32_fp8(u, true);
            a0 += lo[0]; a1 += lo[1]; a2 += hi[0]; a3 += hi[1];
        }
    }
    // combine the two halves
    a0 += __shfl_xor(a0, 32); a1 += __shfl_xor(a1, 32);
    a2 += __shfl_xor(a2, 32); a3 += __shfl_xor(a3, 32);
    if (half == 0) {
        float inv = 1.0f / fmaxf((float)(o1 - o0), 1.0f);
        float4 g = agg4[(size_t)r * 32 + li];
        ushort4 u;
        u.x = f2bf(g.x + a0 * inv); u.y = f2bf(g.y + a1 * inv);
        u.z = f2bf(g.z + a2 * inv); u.w = f2bf(g.w + a3 * inv);
        Xn[(size_t)r * 32 + li] = u;
    }
}

// ---------------- K6: GEMM [NDST,256] x [256,128] + bias + relu, LDS-staged A ----------------
__global__ __launch_bounds__(256) void k_gemm(const float4* __restrict__ Hd4,
                                              const unsigned short* __restrict__ Xn,
                                              const unsigned short* __restrict__ WT,
                                              const float* __restrict__ bias,
                                              float* __restrict__ out) {
    __shared__ __align__(16) unsigned short xt[16][264];
    int r0 = blockIdx.x * 16;
    int t = threadIdx.x;

    // ---- stage A-tile ----
    {
        int row = t >> 4, col8 = (t & 15) * 8;
        const float4* hrow = Hd4 + (size_t)(r0 + row) * 32 + (col8 >> 2);
        float4 p = hrow[0], q = hrow[1];
        bf16x8 hv;
        hv[0] = (short)f2bf(p.x); hv[1] = (short)f2bf(p.y);
        hv[2] = (short)f2bf(p.z); hv[3] = (short)f2bf(p.w);
        hv[4] = (short)f2bf(q.x); hv[5] = (short)f2bf(q.y);
        hv[6] = (short)f2bf(q.z); hv[7] = (short)f2bf(q.w);
        *(bf16x8*)&xt[row][col8] = hv;
        bf16x8 xv = *reinterpret_cast<const bf16x8*>(Xn + (size_t)(r0 + row) * 128 + col8);
        *(bf16x8*)&xt[row][128 + col8] = xv;
    }
    __syncthreads();

    // ---- MFMA phase ----
    int w = t >> 6, lane = t & 63;
    int lr = lane & 15, lg = lane >> 4;
    const bf16x8* B0 = reinterpret_cast<const bf16x8*>(WT + (size_t)(w * 32 + lr) * KK2 + lg * 8);
    const bf16x8* B1 = reinterpret_cast<const bf16x8*>(WT + (size_t)(w * 32 + 16 + lr) * KK2 + lg * 8);

    f32x4 acc0 = {0.f, 0.f, 0.f, 0.f};
    f32x4 acc1 = {0.f, 0.f, 0.f, 0.f};
#pragma unroll
    for (int kk = 0; kk < 8; ++kk) {
        bf16x8 av = *reinterpret_cast<const bf16x8*>(&xt[lr][lg * 8 + kk * 32]);
        acc0 = __builtin_amdgcn_mfma_f32_16x16x32_bf16(av, B0[kk * 4], acc0, 0, 0, 0);
        acc1 = __builtin_amdgcn_mfma_f32_16x16x32_bf16(av, B1[kk * 4], acc1, 0, 0, 0);
    }

    int col0 = w * 32 + lr;
    int col1 = col0 + 16;
    float bi0 = bias[col0], bi1 = bias[col1];
    int rowb = r0 + lg * 4;
#pragma unroll
    for (int j = 0; j < 4; ++j) {
        float v0 = acc0[j] + bi0;
        float v1 = acc1[j] + bi1;
        out[(size_t)(rowb + j) * DOUT + col0] = v0 > 0.f ? v0 : 0.f;
        out[(size_t)(rowb + j) * DOUT + col1] = v1 > 0.f ? v1 : 0.f;
    }
}

extern "C" void kernel_launch(void* const* d_in, const int* in_sizes, int n_in,
                              void* d_out, int out_size, void* d_ws, size_t ws_size,
                              hipStream_t stream) {
    const float* H_src    = (const float*)d_in[0];
    const float* H_dst    = (const float*)d_in[1];
    const float* HBar_src = (const float*)d_in[2];
    const float* agg      = (const float*)d_in[3];
    const float* W        = (const float*)d_in[4];
    const float* bias     = (const float*)d_in[5];
    const int*   src      = (const int*)d_in[6];
    const int*   dst      = (const int*)d_in[7];
    float* out = (float*)d_out;
    const int E = in_sizes[6];

    // ws layout (byte offsets):
    //   bcnt   : 0          .. 1,024      (256 i32, zeroed in prep)
    //   bcur2  : 1,024      .. 2,048
    //   off    : 3,072      .. 203,076    (NDST+1 i32)
    //   pairs  : 203,264    .. 3,403,264  (E u32)
    //   idx    : 3,403,264  .. 6,603,264  (E i32)
    //   WT     : 6,603,264  .. 6,668,800  (128*256 bf16)
    //   hd8    : 6,668,800  .. 19,468,800 (NSRC*128 fp8)
    //   Xn     : 19,468,800 .. 32,268,800 (NDST*128 bf16)
    char* ws = (char*)d_ws;
    int* bcnt            = (int*)ws;
    int* bcur2           = (int*)(ws + 1024);
    int* off             = (int*)(ws + 3072);
    uint32_t* pairs      = (uint32_t*)(ws + 203264);
    int* idx_sorted      = (int*)(ws + 3403264);
    unsigned short* WT   = (unsigned short*)(ws + 6603264);
    unsigned short* hd8  = (unsigned short*)(ws + 6668800);
    unsigned short* Xn   = (unsigned short*)(ws + 19468800);

    const int NBE = (E + CHUNK - 1) / CHUNK;   // 196 binning blocks
    int n8 = NSRC * 16;                        // encode threads, 8 elems each
    int nStream = (n8 + 255) / 256;

    k_prep<<<128, 256, 0, stream>>>(W, WT, bcnt, bcur2);

    k_hd_binA1<<<NBE + nStream, 256, 0, stream>>>(
        (const float4*)H_src, (const float4*)HBar_src, (uint2*)hd8, n8,
        dst, bcnt, E, NBE);

    k_binA2<<<NBE, 256, 0, stream>>>(src, dst, bcnt, bcur2, pairs, E);
    k_binB<<<NBUCK, 256, 0, stream>>>(pairs, bcnt, off, idx_sorted, E);

    k_gath<<<(NDST + 3) / 4, 256, 0, stream>>>(
        (const uint32_t*)hd8, (const float4*)agg, off, idx_sorted,
        (ushort4*)Xn, NDST);

    k_gemm<<<NDST / 16, 256, 0, stream>>>(
        (const float4*)H_dst, Xn, WT, bias, out);
}

// Round 14
// 112.973 us; speedup vs baseline: 1.6605x; 1.0565x over previous
//
#include <hip/hip_runtime.h>
#include <hip/hip_bf16.h>
#include <cstdint>
#include <cstddef>

#define NSRC 100000
#define NDST 50000
#define DOUT 128
#define KK2 256    // 2*D
#define NBUCK 196  // ceil(NDST/256) buckets of 256 dst each
#define CHUNK 4096 // edges per block in binning passes

typedef __attribute__((ext_vector_type(8))) short bf16x8;
typedef __attribute__((ext_vector_type(4))) float f32x4;
typedef __attribute__((ext_vector_type(2))) float f32x2;

static __device__ __forceinline__ unsigned short f2bf(float f) {
    union { float f; uint32_t u; } v; v.f = f;
    uint32_t u = v.u;
    uint32_t r = u + 0x7FFFu + ((u >> 16) & 1u);   // round-to-nearest-even
    return (unsigned short)(r >> 16);
}

// ---------------- K1: prep — WT bf16 convert + zero bucket counters ----------------
__global__ __launch_bounds__(256) void k_prep(const float* __restrict__ W,
                                              unsigned short* __restrict__ WT,
                                              int* __restrict__ bcnt,
                                              int* __restrict__ bcur2) {
    int i = blockIdx.x * 256 + threadIdx.x;
    if (i < DOUT * KK2) {
        int n = i >> 8;    // output col
        int k = i & 255;   // k index
        WT[i] = f2bf(W[k * DOUT + n]);
    }
    if (i < 256) { bcnt[i] = 0; bcur2[i] = 0; }
}

// ---------------- K2: fused hdelta_fp8 stream + bucket histogram (role-split) ----------------
// blocks [0, NBE): LDS-aggregated 196-bucket histogram of dst
// blocks [NBE, ...): fp8 encode stream, ONE float4 per thread (fully dense loads/stores)
__global__ __launch_bounds__(256) void k_hd_binA1(const float4* __restrict__ a,
                                                  const float4* __restrict__ b,
                                                  uint32_t* __restrict__ o, int n4,
                                                  const int* __restrict__ dst,
                                                  int* __restrict__ bcnt,
                                                  int E, int nbe) {
    __shared__ int bh[NBUCK];
    int t = threadIdx.x;
    if ((int)blockIdx.x < nbe) {
        if (t < NBUCK) bh[t] = 0;
        __syncthreads();
        int base = blockIdx.x * CHUNK;
        for (int i = t; i < CHUNK; i += 256) {
            int e = base + i;
            if (e < E) atomicAdd(&bh[dst[e] >> 8], 1);
        }
        __syncthreads();
        if (t < NBUCK && bh[t]) atomicAdd(&bcnt[t], bh[t]);
    } else {
        int i = ((int)blockIdx.x - nbe) * 256 + t;
        if (i < n4) {
            float4 x = a[i], y = b[i];
            uint32_t p = __builtin_amdgcn_cvt_pk_fp8_f32(x.x - y.x, x.y - y.y, 0u, false);
            p = __builtin_amdgcn_cvt_pk_fp8_f32(x.z - y.z, x.w - y.w, p, true);
            o[i] = p;
        }
    }
}

// ---------------- K3: bin edges into bucket regions (scanB folded in) ----------------
__global__ __launch_bounds__(256) void k_binA2(const int* __restrict__ src,
                                               const int* __restrict__ dst,
                                               const int* __restrict__ bcnt,
                                               int* __restrict__ bcur2,
                                               uint32_t* __restrict__ pairs, int E) {
    __shared__ int bh[NBUCK], lcur[NBUCK];
    __shared__ int wsum[4], wex[4];
    int t = threadIdx.x;
    int lane = t & 63, w = t >> 6;

    if (t < NBUCK) bh[t] = 0;
    __syncthreads();
    int base = blockIdx.x * CHUNK;
    for (int i = t; i < CHUNK; i += 256) {
        int e = base + i;
        if (e < E) atomicAdd(&bh[dst[e] >> 8], 1);
    }

    // in-block exclusive scan of bcnt -> bucket base
    int v = (t < NBUCK) ? bcnt[t] : 0;
    int x = v;
#pragma unroll
    for (int s = 1; s < 64; s <<= 1) { int tt = __shfl_up(x, s, 64); if (lane >= s) x += tt; }
    if (lane == 63) wsum[w] = x;
    __syncthreads();
    if (t == 0) {
        int run = 0;
#pragma unroll
        for (int k = 0; k < 4; ++k) { wex[k] = run; run += wsum[k]; }
    }
    __syncthreads();
    int ex = wex[w] + x - v;

    if (t < NBUCK) lcur[t] = bh[t] ? (ex + atomicAdd(&bcur2[t], bh[t])) : 0;
    __syncthreads();

    for (int i = t; i < CHUNK; i += 256) {
        int e = base + i;
        if (e < E) {
            int d = dst[e];
            int pos = atomicAdd(&lcur[d >> 8], 1);
            pairs[pos] = ((uint32_t)(d & 255) << 24) | (uint32_t)src[e];
        }
    }
}

// ---------------- K4: per-bucket local sort: off[] + idx[] ----------------
__global__ __launch_bounds__(256) void k_binB(const uint32_t* __restrict__ pairs,
                                              const int* __restrict__ bcnt,
                                              int* __restrict__ off,
                                              int* __restrict__ idx, int E) {
    __shared__ int lcnt[256];
    __shared__ int lcur[256];
    __shared__ int wsum[4], wex[4];
    __shared__ int gbase_s;
    int b = blockIdx.x, t = threadIdx.x;
    int lane = t & 63, w = t >> 6;

    // in-block exclusive scan of bcnt -> this bucket's base
    int v = (t < NBUCK) ? bcnt[t] : 0;
    int x = v;
#pragma unroll
    for (int s = 1; s < 64; s <<= 1) { int tt = __shfl_up(x, s, 64); if (lane >= s) x += tt; }
    if (lane == 63) wsum[w] = x;
    __syncthreads();
    if (t == 0) {
        int run = 0;
#pragma unroll
        for (int k = 0; k < 4; ++k) { wex[k] = run; run += wsum[k]; }
    }
    __syncthreads();
    if (t == b) gbase_s = wex[w] + x - v;
    lcnt[t] = 0;
    __syncthreads();
    int gbase = gbase_s;
    int cnt = bcnt[b];

    for (int i = t; i < cnt; i += 256)
        atomicAdd(&lcnt[pairs[gbase + i] >> 24], 1);
    __syncthreads();

    // block-wide exclusive scan of lcnt
    v = lcnt[t];
    x = v;
#pragma unroll
    for (int s = 1; s < 64; s <<= 1) { int tt = __shfl_up(x, s, 64); if (lane >= s) x += tt; }
    if (lane == 63) wsum[w] = x;
    __syncthreads();
    if (t == 0) {
        int run = 0;
#pragma unroll
        for (int k = 0; k < 4; ++k) { wex[k] = run; run += wsum[k]; }
    }
    __syncthreads();
    int ex = wex[w] + x - v;
    lcur[t] = ex;
    int d = b * 256 + t;
    if (d < NDST) off[d] = gbase + ex;
    if (b == 0 && t == 0) off[NDST] = E;
    __syncthreads();

    for (int i = t; i < cnt; i += 256) {
        uint32_t p = pairs[gbase + i];
        int pos = atomicAdd(&lcur[p >> 24], 1);
        idx[gbase + pos] = (int)(p & 0xFFFFFFu);
    }
}

// ---------------- K5: barrier-free gather-mean-agg -> Xn (h_neigh, bf16) ----------------
// 4 waves/block, ONE dst row per wave, no barrier. Half-wave gathers: lane owns
// 4 cols (uint = 4 fp8); two halves gather 2 edges/round; MASKED FULL-UNROLL —
// 16 edges (8 loads) per round always issue, OOB edges masked to 0 (shfl of
// lane>=m yields 0 -> row-0 load, L1-hot, result zeroed). No serial tail.
__global__ __launch_bounds__(256) void k_gath(const uint32_t* __restrict__ hd8u,
                                              const float4* __restrict__ agg4,
                                              const int* __restrict__ off,
                                              const int* __restrict__ idx,
                                              ushort4* __restrict__ Xn, int n) {
    int r = blockIdx.x * 4 + (threadIdx.x >> 6);
    if (r >= n) return;
    int lane = threadIdx.x & 63;
    int li = lane & 31, half = lane >> 5;
    float a0 = 0.f, a1 = 0.f, a2 = 0.f, a3 = 0.f;
    int o0 = off[r], o1 = off[r + 1];
    for (int c = o0; c < o1; c += 64) {
        int m = o1 - c; if (m > 64) m = 64;
        int myi = (lane < m) ? idx[c + lane] : 0;
        for (int j = 0; j < m; j += 16) {
            int t0 = j + 0 + half,  t1 = j + 2 + half,  t2 = j + 4 + half,  t3 = j + 6 + half;
            int t4 = j + 8 + half,  t5 = j + 10 + half, t6 = j + 12 + half, t7 = j + 14 + half;
            int s0 = __shfl(myi, t0), s1 = __shfl(myi, t1);
            int s2 = __shfl(myi, t2), s3 = __shfl(myi, t3);
            int s4 = __shfl(myi, t4), s5 = __shfl(myi, t5);
            int s6 = __shfl(myi, t6), s7 = __shfl(myi, t7);
            uint32_t u0 = hd8u[(size_t)s0 * 32 + li];
            uint32_t u1 = hd8u[(size_t)s1 * 32 + li];
            uint32_t u2 = hd8u[(size_t)s2 * 32 + li];
            uint32_t u3 = hd8u[(size_t)s3 * 32 + li];
            uint32_t u4 = hd8u[(size_t)s4 * 32 + li];
            uint32_t u5 = hd8u[(size_t)s5 * 32 + li];
            uint32_t u6 = hd8u[(size_t)s6 * 32 + li];
            uint32_t u7 = hd8u[(size_t)s7 * 32 + li];
            if (t0 >= m) u0 = 0;  if (t1 >= m) u1 = 0;
            if (t2 >= m) u2 = 0;  if (t3 >= m) u3 = 0;
            if (t4 >= m) u4 = 0;  if (t5 >= m) u5 = 0;
            if (t6 >= m) u6 = 0;  if (t7 >= m) u7 = 0;
            f32x2 l0 = __builtin_amdgcn_cvt_pk_f32_fp8(u0, false);
            f32x2 h0 = __builtin_amdgcn_cvt_pk_f32_fp8(u0, true);
            f32x2 l1 = __builtin_amdgcn_cvt_pk_f32_fp8(u1, false);
            f32x2 h1 = __builtin_amdgcn_cvt_pk_f32_fp8(u1, true);
            f32x2 l2 = __builtin_amdgcn_cvt_pk_f32_fp8(u2, false);
            f32x2 h2 = __builtin_amdgcn_cvt_pk_f32_fp8(u2, true);
            f32x2 l3 = __builtin_amdgcn_cvt_pk_f32_fp8(u3, false);
            f32x2 h3 = __builtin_amdgcn_cvt_pk_f32_fp8(u3, true);
            f32x2 l4 = __builtin_amdgcn_cvt_pk_f32_fp8(u4, false);
            f32x2 h4 = __builtin_amdgcn_cvt_pk_f32_fp8(u4, true);
            f32x2 l5 = __builtin_amdgcn_cvt_pk_f32_fp8(u5, false);
            f32x2 h5 = __builtin_amdgcn_cvt_pk_f32_fp8(u5, true);
            f32x2 l6 = __builtin_amdgcn_cvt_pk_f32_fp8(u6, false);
            f32x2 h6 = __builtin_amdgcn_cvt_pk_f32_fp8(u6, true);
            f32x2 l7 = __builtin_amdgcn_cvt_pk_f32_fp8(u7, false);
            f32x2 h7 = __builtin_amdgcn_cvt_pk_f32_fp8(u7, true);
            a0 += l0[0] + l1[0] + l2[0] + l3[0] + l4[0] + l5[0] + l6[0] + l7[0];
            a1 += l0[1] + l1[1] + l2[1] + l3[1] + l4[1] + l5[1] + l6[1] + l7[1];
            a2 += h0[0] + h1[0] + h2[0] + h3[0] + h4[0] + h5[0] + h6[0] + h7[0];
            a3 += h0[1] + h1[1] + h2[1] + h3[1] + h4[1] + h5[1] + h6[1] + h7[1];
        }
    }
    // combine the two halves
    a0 += __shfl_xor(a0, 32); a1 += __shfl_xor(a1, 32);
    a2 += __shfl_xor(a2, 32); a3 += __shfl_xor(a3, 32);
    if (half == 0) {
        float inv = 1.0f / fmaxf((float)(o1 - o0), 1.0f);
        float4 g = agg4[(size_t)r * 32 + li];
        ushort4 u;
        u.x = f2bf(g.x + a0 * inv); u.y = f2bf(g.y + a1 * inv);
        u.z = f2bf(g.z + a2 * inv); u.w = f2bf(g.w + a3 * inv);
        Xn[(size_t)r * 32 + li] = u;
    }
}

// ---------------- K6: GEMM [NDST,256] x [256,128] + bias + relu, LDS-staged A ----------------
__global__ __launch_bounds__(256) void k_gemm(const float4* __restrict__ Hd4,
                                              const unsigned short* __restrict__ Xn,
                                              const unsigned short* __restrict__ WT,
                                              const float* __restrict__ bias,
                                              float* __restrict__ out) {
    __shared__ __align__(16) unsigned short xt[16][264];
    int r0 = blockIdx.x * 16;
    int t = threadIdx.x;

    // ---- stage A-tile (dense loads) ----
    {
        // H_dst half: tile = 16 rows x 32 float4; thread t takes flat f4 #t and #(t+256)
#pragma unroll
        for (int p = 0; p < 2; ++p) {
            int f = t + p * 256;
            int row = f >> 5, c4 = f & 31;
            float4 v = Hd4[(size_t)(r0 + row) * 32 + c4];
            ushort4 u;
            u.x = f2bf(v.x); u.y = f2bf(v.y); u.z = f2bf(v.z); u.w = f2bf(v.w);
            *(ushort4*)&xt[row][c4 * 4] = u;
        }
        // Xn half: 16 rows x 128 bf16; thread t takes 8 bf16 (dense 16B)
        int row = t >> 4, col8 = (t & 15) * 8;
        bf16x8 xv = *reinterpret_cast<const bf16x8*>(Xn + (size_t)(r0 + row) * 128 + col8);
        *(bf16x8*)&xt[row][128 + col8] = xv;
    }
    __syncthreads();

    // ---- MFMA phase ----
    int w = t >> 6, lane = t & 63;
    int lr = lane & 15, lg = lane >> 4;
    const bf16x8* B0 = reinterpret_cast<const bf16x8*>(WT + (size_t)(w * 32 + lr) * KK2 + lg * 8);
    const bf16x8* B1 = reinterpret_cast<const bf16x8*>(WT + (size_t)(w * 32 + 16 + lr) * KK2 + lg * 8);

    f32x4 acc0 = {0.f, 0.f, 0.f, 0.f};
    f32x4 acc1 = {0.f, 0.f, 0.f, 0.f};
#pragma unroll
    for (int kk = 0; kk < 8; ++kk) {
        bf16x8 av = *reinterpret_cast<const bf16x8*>(&xt[lr][lg * 8 + kk * 32]);
        acc0 = __builtin_amdgcn_mfma_f32_16x16x32_bf16(av, B0[kk * 4], acc0, 0, 0, 0);
        acc1 = __builtin_amdgcn_mfma_f32_16x16x32_bf16(av, B1[kk * 4], acc1, 0, 0, 0);
    }

    int col0 = w * 32 + lr;
    int col1 = col0 + 16;
    float bi0 = bias[col0], bi1 = bias[col1];
    int rowb = r0 + lg * 4;
#pragma unroll
    for (int j = 0; j < 4; ++j) {
        float v0 = acc0[j] + bi0;
        float v1 = acc1[j] + bi1;
        out[(size_t)(rowb + j) * DOUT + col0] = v0 > 0.f ? v0 : 0.f;
        out[(size_t)(rowb + j) * DOUT + col1] = v1 > 0.f ? v1 : 0.f;
    }
}

extern "C" void kernel_launch(void* const* d_in, const int* in_sizes, int n_in,
                              void* d_out, int out_size, void* d_ws, size_t ws_size,
                              hipStream_t stream) {
    const float* H_src    = (const float*)d_in[0];
    const float* H_dst    = (const float*)d_in[1];
    const float* HBar_src = (const float*)d_in[2];
    const float* agg      = (const float*)d_in[3];
    const float* W        = (const float*)d_in[4];
    const float* bias     = (const float*)d_in[5];
    const int*   src      = (const int*)d_in[6];
    const int*   dst      = (const int*)d_in[7];
    float* out = (float*)d_out;
    const int E = in_sizes[6];

    // ws layout (byte offsets):
    //   bcnt   : 0          .. 1,024      (256 i32, zeroed in prep)
    //   bcur2  : 1,024      .. 2,048
    //   off    : 3,072      .. 203,076    (NDST+1 i32)
    //   pairs  : 203,264    .. 3,403,264  (E u32)
    //   idx    : 3,403,264  .. 6,603,264  (E i32)
    //   WT     : 6,603,264  .. 6,668,800  (128*256 bf16)
    //   hd8    : 6,668,800  .. 19,468,800 (NSRC*128 fp8)
    //   Xn     : 19,468,800 .. 32,268,800 (NDST*128 bf16)
    char* ws = (char*)d_ws;
    int* bcnt            = (int*)ws;
    int* bcur2           = (int*)(ws + 1024);
    int* off             = (int*)(ws + 3072);
    uint32_t* pairs      = (uint32_t*)(ws + 203264);
    int* idx_sorted      = (int*)(ws + 3403264);
    unsigned short* WT   = (unsigned short*)(ws + 6603264);
    unsigned short* hd8  = (unsigned short*)(ws + 6668800);
    unsigned short* Xn   = (unsigned short*)(ws + 19468800);

    const int NBE = (E + CHUNK - 1) / CHUNK;   // 196 binning blocks
    int n4 = NSRC * 32;                        // float4 count (one per thread)
    int nStream = (n4 + 255) / 256;

    k_prep<<<128, 256, 0, stream>>>(W, WT, bcnt, bcur2);

    k_hd_binA1<<<NBE + nStream, 256, 0, stream>>>(
        (const float4*)H_src, (const float4*)HBar_src, (uint32_t*)hd8, n4,
        dst, bcnt, E, NBE);

    k_binA2<<<NBE, 256, 0, stream>>>(src, dst, bcnt, bcur2, pairs, E);
    k_binB<<<NBUCK, 256, 0, stream>>>(pairs, bcnt, off, idx_sorted, E);

    k_gath<<<(NDST + 3) / 4, 256, 0, stream>>>(
        (const uint32_t*)hd8, (const float4*)agg, off, idx_sorted,
        (ushort4*)Xn, NDST);

    k_gemm<<<NDST / 16, 256, 0, stream>>>(
        (const float4*)H_dst, Xn, WT, bias, out);
}